// Round 1
// baseline (22231.113 us; speedup 1.0000x reference)
//
#include <hip/hip_runtime.h>
#include <math.h>

// Problem dims
#define TB   100
#define BB   256
#define INF_ 784
#define HH   200
#define RR   4
#define NN   128
#define DD   40
#define NCLS 5
#define G4H  800   // 4*H
#define KAW  324   // 160 key + 160 add + 1 sigma + 3 pad
#define MST  41    // padded LDS row stride for M (bank-conflict-free)

__device__ __forceinline__ float sigmoidf_(float x) { return 1.0f / (1.0f + expf(-x)); }

// ---------------------------------------------------------------------------
// Prep: transpose weights into GEMV-friendly (k-major) layouts in workspace.
// WhhT: (200,800)  WrhT: (160,200)  WkaT: (200,324) = [Wkey|Wadd|Wsig|pad]^T
// ---------------------------------------------------------------------------
__global__ __launch_bounds__(256) void prep_kernel(
    const float* __restrict__ Whh, const float* __restrict__ Wrh,
    const float* __restrict__ Wkey, const float* __restrict__ Wadd,
    const float* __restrict__ Wsig, const float* __restrict__ bkey,
    const float* __restrict__ badd, const float* __restrict__ bsig,
    float* __restrict__ WhhT, float* __restrict__ WrhT,
    float* __restrict__ WkaT, float* __restrict__ bka)
{
  const int tid = blockIdx.x * 256 + threadIdx.x;
  if (tid < 160000) {            // Whh (800,200) -> WhhT (200,800)
    const int j = tid / 200, k = tid - j * 200;
    WhhT[k * G4H + j] = Whh[tid];
  }
  if (tid < 32000) {             // Wrh (200,160) -> WrhT (160,200)
    const int k = tid / 160, m = tid - k * 160;
    WrhT[m * HH + k] = Wrh[tid];
  }
  if (tid < 200 * KAW) {         // [Wkey(160,200)|Wadd(160,200)|Wsig(1,200)]^T
    const int k = tid / KAW, j = tid - k * KAW;
    float v = 0.0f;
    if (j < 160)       v = Wkey[j * HH + k];
    else if (j < 320)  v = Wadd[(j - 160) * HH + k];
    else if (j == 320) v = Wsig[k];
    WkaT[tid] = v;
  }
  if (tid < KAW) {
    float v = 0.0f;
    if (tid < 160)       v = bkey[tid];
    else if (tid < 320)  v = badd[tid - 160];
    else if (tid == 320) v = bsig[0];
    bka[tid] = v;
  }
}

// ---------------------------------------------------------------------------
// Big GEMM: G[m, j] = sum_k x[m,k]*Wih[j,k] + bih[j] + bhh[j]
// m = b*T + t (25600 rows), j < 800, k < 784. Classic 64x64x16 fp32 tile.
// ---------------------------------------------------------------------------
__global__ __launch_bounds__(256) void gemm_in_kernel(
    const float* __restrict__ X, const float* __restrict__ Wih,
    const float* __restrict__ bih, const float* __restrict__ bhh,
    float* __restrict__ G)
{
  __shared__ float As[16 * 68];   // [k][m], stride 68 keeps 16B alignment + few conflicts
  __shared__ float Bs[16 * 68];   // [k][n]
  const int tid  = threadIdx.x;
  const int tx   = tid & 15, ty = tid >> 4;
  const int lrow = tid >> 2, lk = (tid & 3) * 4;
  const int n0 = blockIdx.x * 64;
  const int m0 = blockIdx.y * 64;
  const int jg = n0 + lrow;
  const float* Xp = X   + (size_t)(m0 + lrow) * INF_ + lk;
  const float* Wp = Wih + (size_t)jg * INF_ + lk;

  float acc[4][4];
#pragma unroll
  for (int i = 0; i < 4; ++i)
#pragma unroll
    for (int j = 0; j < 4; ++j) acc[i][j] = 0.f;

  for (int k0 = 0; k0 < INF_; k0 += 16) {
    const float4 a = *(const float4*)(Xp + k0);
    const float4 b = (jg < G4H) ? *(const float4*)(Wp + k0)
                                : make_float4(0.f, 0.f, 0.f, 0.f);
    __syncthreads();
    const float av[4] = {a.x, a.y, a.z, a.w};
    const float bv[4] = {b.x, b.y, b.z, b.w};
#pragma unroll
    for (int u = 0; u < 4; ++u) {
      As[(lk + u) * 68 + lrow] = av[u];
      Bs[(lk + u) * 68 + lrow] = bv[u];
    }
    __syncthreads();
#pragma unroll
    for (int k = 0; k < 16; ++k) {
      const float4 a4 = *(const float4*)&As[k * 68 + ty * 4];
      const float4 b4 = *(const float4*)&Bs[k * 68 + tx * 4];
      const float aa[4] = {a4.x, a4.y, a4.z, a4.w};
      const float bb[4] = {b4.x, b4.y, b4.z, b4.w};
#pragma unroll
      for (int i = 0; i < 4; ++i)
#pragma unroll
        for (int j = 0; j < 4; ++j) acc[i][j] += aa[i] * bb[j];
    }
  }
  const int jc = n0 + tx * 4;
  if (jc < G4H) {
    float bs[4];
#pragma unroll
    for (int u = 0; u < 4; ++u) bs[u] = bih[jc + u] + bhh[jc + u];
#pragma unroll
    for (int i = 0; i < 4; ++i) {
      const size_t m = (size_t)m0 + ty * 4 + i;
      const float4 v = make_float4(acc[i][0] + bs[0], acc[i][1] + bs[1],
                                   acc[i][2] + bs[2], acc[i][3] + bs[3]);
      *(float4*)(G + m * G4H + jc) = v;
    }
  }
}

// ---------------------------------------------------------------------------
// Recurrence: one block per batch element, T-loop inside, all state in LDS.
// ---------------------------------------------------------------------------
__global__ __launch_bounds__(256) void mann_kernel(
    const float* __restrict__ G,
    const float* __restrict__ WhhT,
    const float* __restrict__ WrhT,
    const float* __restrict__ WkaT,
    const float* __restrict__ bka,
    const float* __restrict__ brh,
    const float* __restrict__ Who, const float* __restrict__ bho,
    const float* __restrict__ Wro, const float* __restrict__ bro,
    float* __restrict__ out)
{
  __shared__ float M_s[NN * MST];
  __shared__ float h_s[HH], c_s[HH], r_s[RR * DD], brh_s[HH];
  __shared__ float wr_s[RR * NN], K_s[RR * NN], ww_s[RR * NN];
  __shared__ float wu_s[NN], Mn2_s[NN], kn2_s[RR];
  __shared__ float gates_s[G4H];
  __shared__ float ka_s[KAW];
  __shared__ int   lu_s[RR];

  const int tid = threadIdx.x;
  const int b   = blockIdx.x;

  for (int e = tid; e < NN * MST; e += 256) M_s[e] = 0.f;
  for (int e = tid; e < RR * NN; e += 256)  wr_s[e] = 0.f;
  if (tid < NN) wu_s[tid] = 0.f;
  if (tid < HH) { h_s[tid] = 0.f; c_s[tid] = 0.f; brh_s[tid] = brh[tid]; }
  if (tid < RR * DD) r_s[tid] = 0.f;
  __syncthreads();

  const float4* WhhT4 = (const float4*)WhhT;  // row stride 200 float4
  const float4* WkaT4 = (const float4*)WkaT;  // row stride 81 float4
  const float4* bka4  = (const float4*)bka;

#pragma clang loop unroll(disable)
  for (int t = 0; t < TB; ++t) {
    // (1) h = h + r @ Wrh^T + brh
    if (tid < HH) {
      float acc = h_s[tid] + brh_s[tid];
      for (int m0 = 0; m0 < RR * DD; m0 += 8) {
        float w[8];
#pragma unroll
        for (int u = 0; u < 8; ++u) w[u] = WrhT[(m0 + u) * HH + tid];
#pragma unroll
        for (int u = 0; u < 8; ++u) acc += r_s[m0 + u] * w[u];
      }
      h_s[tid] = acc;
    }
    __syncthreads();

    // (2) gates = G (has x@Wih^T + bih + bhh) + h @ Whh^T
    if (tid < 200) {
      float4 acc = *(const float4*)(G + ((size_t)b * TB + t) * G4H + tid * 4);
      for (int k0 = 0; k0 < HH; k0 += 8) {
        float4 w[8];
#pragma unroll
        for (int u = 0; u < 8; ++u) w[u] = WhhT4[(k0 + u) * 200 + tid];
#pragma unroll
        for (int u = 0; u < 8; ++u) {
          const float hk = h_s[k0 + u];
          acc.x += hk * w[u].x; acc.y += hk * w[u].y;
          acc.z += hk * w[u].z; acc.w += hk * w[u].w;
        }
      }
      *(float4*)(gates_s + tid * 4) = acc;
    }
    __syncthreads();

    // (3) LSTM pointwise
    if (tid < HH) {
      const float ig = sigmoidf_(gates_s[tid]);
      const float fg = sigmoidf_(gates_s[HH + tid]);
      const float gg = tanhf(gates_s[2 * HH + tid]);
      const float og = sigmoidf_(gates_s[3 * HH + tid]);
      const float cn = fg * c_s[tid] + ig * gg;
      c_s[tid] = cn;
      h_s[tid] = og * tanhf(cn);
    }
    __syncthreads();

    // (4) [key | add | sigma] = bka + h @ Wka^T
    if (tid < 81) {
      float4 acc = bka4[tid];
      for (int k0 = 0; k0 < HH; k0 += 8) {
        float4 w[8];
#pragma unroll
        for (int u = 0; u < 8; ++u) w[u] = WkaT4[(k0 + u) * 81 + tid];
#pragma unroll
        for (int u = 0; u < 8; ++u) {
          const float hk = h_s[k0 + u];
          acc.x += hk * w[u].x; acc.y += hk * w[u].y;
          acc.z += hk * w[u].z; acc.w += hk * w[u].w;
        }
      }
      *(float4*)(ka_s + tid * 4) = acc;
    }
    __syncthreads();

    // (5) least-used R slots (wave 0, stable tie-break = smaller index) + key norms
    if (tid < 64) {
      const int l = tid;
      unsigned u0 = __float_as_uint(wu_s[l]);
      unsigned u1 = __float_as_uint(wu_s[l + 64]);
      if (u0 == 0x80000000u) u0 = 0u;   // -0 -> +0
      if (u1 == 0x80000000u) u1 = 0u;
      u0 = (u0 & 0x80000000u) ? ~u0 : (u0 | 0x80000000u);
      u1 = (u1 & 0x80000000u) ? ~u1 : (u1 | 0x80000000u);
      unsigned long long k0 = ((unsigned long long)u0 << 32) | (unsigned)l;
      unsigned long long k1 = ((unsigned long long)u1 << 32) | (unsigned)(l + 64);
#pragma unroll
      for (int rsel = 0; rsel < RR; ++rsel) {
        unsigned long long mn = (k0 < k1) ? k0 : k1;
#pragma unroll
        for (int off = 32; off; off >>= 1) {
          const unsigned long long o = __shfl_xor(mn, off);
          if (o < mn) mn = o;
        }
        const int idx = (int)(mn & 0xFFFFFFFFull);
        if (l == 0) lu_s[rsel] = idx;
        if (idx == l)      k0 = ~0ull;
        if (idx == l + 64) k1 = ~0ull;
      }
    } else if (tid < 68) {
      const int q = tid - 64;
      float s = 0.f;
#pragma unroll
      for (int d = 0; d < DD; ++d) { const float v = ka_s[q * DD + d]; s += v * v; }
      kn2_s[q] = s;
    }
    __syncthreads();

    // (6) ww = sigma*wr + (1-sigma)*wlu
    {
      const float sg = ka_s[320];
      const int l0 = lu_s[0], l1 = lu_s[1], l2 = lu_s[2], l3 = lu_s[3];
      for (int e = tid; e < RR * NN; e += 256) {
        const int n = e & (NN - 1);
        const float wlu = (n == l0 || n == l1 || n == l2 || n == l3) ? 1.f : 0.f;
        ww_s[e] = sg * wr_s[e] + (1.f - sg) * wlu;
      }
    }
    __syncthreads();

    // (7) M = M*wlu + ww^T @ add
    {
      const int l0 = lu_s[0], l1 = lu_s[1], l2 = lu_s[2], l3 = lu_s[3];
      for (int e = tid; e < NN * DD; e += 256) {
        const int n = e / DD, d = e - n * DD;
        const float wlu = (n == l0 || n == l1 || n == l2 || n == l3) ? 1.f : 0.f;
        float acc = M_s[n * MST + d] * wlu;
#pragma unroll
        for (int q = 0; q < RR; ++q) acc += ww_s[q * NN + n] * ka_s[160 + q * DD + d];
        M_s[n * MST + d] = acc;
      }
    }
    __syncthreads();

    // (7b) M row norms
    if (tid < NN) {
      float s = 0.f;
#pragma unroll 8
      for (int d = 0; d < DD; ++d) { const float v = M_s[tid * MST + d]; s += v * v; }
      Mn2_s[tid] = s;
    }
    __syncthreads();

    // (8) K = cosine(key, M)
    for (int e = tid; e < RR * NN; e += 256) {
      const int q = e >> 7, n = e & (NN - 1);
      float s = 0.f;
#pragma unroll 8
      for (int d = 0; d < DD; ++d) s += ka_s[q * DD + d] * M_s[n * MST + d];
      K_s[e] = s / sqrtf(kn2_s[q] * Mn2_s[n] + 1e-6f);
    }
    __syncthreads();

    // (9) softmax over N, one wave per head row
    {
      const int w = tid >> 6, l = tid & 63;
      const float v0 = K_s[w * NN + l], v1 = K_s[w * NN + 64 + l];
      float mx = fmaxf(v0, v1);
#pragma unroll
      for (int off = 32; off; off >>= 1) mx = fmaxf(mx, __shfl_xor(mx, off));
      const float e0 = expf(v0 - mx), e1 = expf(v1 - mx);
      float s = e0 + e1;
#pragma unroll
      for (int off = 32; off; off >>= 1) s += __shfl_xor(s, off);
      const float inv = 1.f / s;
      K_s[w * NN + l]      = e0 * inv;
      K_s[w * NN + 64 + l] = e1 * inv;
    }
    __syncthreads();

    // (10) r_t = wr_t @ M  and  (11) wu = gamma*wu + sum_r(wr_t + ww)
    if (tid < RR * DD) {
      const int q = tid / DD, d = tid - q * DD;
      float acc = 0.f;
      for (int n = 0; n < NN; ++n) acc += K_s[q * NN + n] * M_s[n * MST + d];
      r_s[tid] = acc;
    }
    if (tid < NN) {
      float s = 0.95f * wu_s[tid];
#pragma unroll
      for (int q = 0; q < RR; ++q) s += K_s[q * NN + tid] + ww_s[q * NN + tid];
      wu_s[tid] = s;
    }
    __syncthreads();

    // (12) out_t = h@Who^T + bho + r@Wro^T + bro (wave 0); waves 1-3: wr <- wr_t
    if (tid < 64) {
      const int l = tid;
      const size_t ob = ((size_t)b * TB + t) * NCLS;
#pragma unroll
      for (int j = 0; j < NCLS; ++j) {
        float p = 0.f;
        for (int k = l; k < HH; k += 64)      p += h_s[k] * Who[j * HH + k];
        for (int m = l; m < RR * DD; m += 64) p += r_s[m] * Wro[j * (RR * DD) + m];
#pragma unroll
        for (int off = 32; off; off >>= 1) p += __shfl_xor(p, off);
        if (l == 0) out[ob + j] = p + bho[j] + bro[j];
      }
    } else {
      for (int e = tid - 64; e < RR * NN; e += 192) wr_s[e] = K_s[e];
    }
    __syncthreads();
  }
}

// ---------------------------------------------------------------------------
extern "C" void kernel_launch(void* const* d_in, const int* in_sizes, int n_in,
                              void* d_out, int out_size, void* d_ws, size_t ws_size,
                              hipStream_t stream) {
  const float* x    = (const float*)d_in[0];
  const float* Wkey = (const float*)d_in[1];
  const float* bkey = (const float*)d_in[2];
  const float* Wadd = (const float*)d_in[3];
  const float* badd = (const float*)d_in[4];
  const float* Wsig = (const float*)d_in[5];
  const float* bsig = (const float*)d_in[6];
  const float* Who  = (const float*)d_in[7];
  const float* bho  = (const float*)d_in[8];
  const float* Wro  = (const float*)d_in[9];
  const float* bro  = (const float*)d_in[10];
  const float* Wrh  = (const float*)d_in[11];
  const float* brh  = (const float*)d_in[12];
  const float* Wih  = (const float*)d_in[13];
  const float* bih  = (const float*)d_in[14];
  const float* Whh  = (const float*)d_in[15];
  const float* bhh  = (const float*)d_in[16];

  float* ws   = (float*)d_ws;
  float* G    = ws;                       // 25600*800 = 20,480,000
  float* WhhT = G + (size_t)25600 * 800;  // 160,000
  float* WrhT = WhhT + 160000;            // 32,000
  float* WkaT = WrhT + 32000;             // 64,800
  float* bka  = WkaT + 64800;             // 324

  prep_kernel<<<(160000 + 255) / 256, 256, 0, stream>>>(
      Whh, Wrh, Wkey, Wadd, Wsig, bkey, badd, bsig, WhhT, WrhT, WkaT, bka);

  dim3 gA((G4H + 63) / 64, 25600 / 64);
  gemm_in_kernel<<<gA, 256, 0, stream>>>(x, Wih, bih, bhh, G);

  mann_kernel<<<BB, 256, 0, stream>>>(G, WhhT, WrhT, WkaT, bka, brh,
                                      Who, bho, Wro, bro, (float*)d_out);
}

// Round 2
// 16961.797 us; speedup vs baseline: 1.3107x; 1.3107x over previous
//
#include <hip/hip_runtime.h>
#include <math.h>

// Problem dims
#define TB   100
#define BB   256
#define INF_ 784
#define HH   200
#define RR   4
#define NN   128
#define DD   40
#define NCLS 5
#define G4H  800   // 4*H
#define KAW  324   // 160 key + 160 add + 1 sigma + 3 pad
#define MST  41    // padded LDS row stride for M

__device__ __forceinline__ float sigmoidf_(float x) { return 1.0f / (1.0f + expf(-x)); }

// ---------------------------------------------------------------------------
// Prep: transpose weights into GEMV-friendly (k-major) layouts in workspace.
// WhhT: (200,800)  WrhT: (160,200)  WkaT: (200,324) = [Wkey|Wadd|Wsig|pad]^T
// ---------------------------------------------------------------------------
__global__ __launch_bounds__(256) void prep_kernel(
    const float* __restrict__ Whh, const float* __restrict__ Wrh,
    const float* __restrict__ Wkey, const float* __restrict__ Wadd,
    const float* __restrict__ Wsig, const float* __restrict__ bkey,
    const float* __restrict__ badd, const float* __restrict__ bsig,
    float* __restrict__ WhhT, float* __restrict__ WrhT,
    float* __restrict__ WkaT, float* __restrict__ bka)
{
  const int tid = blockIdx.x * 256 + threadIdx.x;
  if (tid < 160000) {            // Whh (800,200) -> WhhT (200,800)
    const int j = tid / 200, k = tid - j * 200;
    WhhT[k * G4H + j] = Whh[tid];
  }
  if (tid < 32000) {             // Wrh (200,160) -> WrhT (160,200)
    const int k = tid / 160, m = tid - k * 160;
    WrhT[m * HH + k] = Wrh[tid];
  }
  if (tid < 200 * KAW) {         // [Wkey(160,200)|Wadd(160,200)|Wsig(1,200)]^T
    const int k = tid / KAW, j = tid - k * KAW;
    float v = 0.0f;
    if (j < 160)       v = Wkey[j * HH + k];
    else if (j < 320)  v = Wadd[(j - 160) * HH + k];
    else if (j == 320) v = Wsig[k];
    WkaT[tid] = v;
  }
  if (tid < KAW) {
    float v = 0.0f;
    if (tid < 160)       v = bkey[tid];
    else if (tid < 320)  v = badd[tid - 160];
    else if (tid == 320) v = bsig[0];
    bka[tid] = v;
  }
}

// ---------------------------------------------------------------------------
// Big GEMM: G[m, j] = sum_k x[m,k]*Wih[j,k] + bih[j] + bhh[j]
// ---------------------------------------------------------------------------
__global__ __launch_bounds__(256) void gemm_in_kernel(
    const float* __restrict__ X, const float* __restrict__ Wih,
    const float* __restrict__ bih, const float* __restrict__ bhh,
    float* __restrict__ G)
{
  __shared__ float As[16 * 68];
  __shared__ float Bs[16 * 68];
  const int tid  = threadIdx.x;
  const int tx   = tid & 15, ty = tid >> 4;
  const int lrow = tid >> 2, lk = (tid & 3) * 4;
  const int n0 = blockIdx.x * 64;
  const int m0 = blockIdx.y * 64;
  const int jg = n0 + lrow;
  const float* Xp = X   + (size_t)(m0 + lrow) * INF_ + lk;
  const float* Wp = Wih + (size_t)jg * INF_ + lk;

  float acc[4][4];
#pragma unroll
  for (int i = 0; i < 4; ++i)
#pragma unroll
    for (int j = 0; j < 4; ++j) acc[i][j] = 0.f;

  for (int k0 = 0; k0 < INF_; k0 += 16) {
    const float4 a = *(const float4*)(Xp + k0);
    const float4 b = (jg < G4H) ? *(const float4*)(Wp + k0)
                                : make_float4(0.f, 0.f, 0.f, 0.f);
    __syncthreads();
    const float av[4] = {a.x, a.y, a.z, a.w};
    const float bv[4] = {b.x, b.y, b.z, b.w};
#pragma unroll
    for (int u = 0; u < 4; ++u) {
      As[(lk + u) * 68 + lrow] = av[u];
      Bs[(lk + u) * 68 + lrow] = bv[u];
    }
    __syncthreads();
#pragma unroll
    for (int k = 0; k < 16; ++k) {
      const float4 a4 = *(const float4*)&As[k * 68 + ty * 4];
      const float4 b4 = *(const float4*)&Bs[k * 68 + tx * 4];
      const float aa[4] = {a4.x, a4.y, a4.z, a4.w};
      const float bb[4] = {b4.x, b4.y, b4.z, b4.w};
#pragma unroll
      for (int i = 0; i < 4; ++i)
#pragma unroll
        for (int j = 0; j < 4; ++j) acc[i][j] += aa[i] * bb[j];
    }
  }
  const int jc = n0 + tx * 4;
  if (jc < G4H) {
    float bs[4];
#pragma unroll
    for (int u = 0; u < 4; ++u) bs[u] = bih[jc + u] + bhh[jc + u];
#pragma unroll
    for (int i = 0; i < 4; ++i) {
      const size_t m = (size_t)m0 + ty * 4 + i;
      const float4 v = make_float4(acc[i][0] + bs[0], acc[i][1] + bs[1],
                                   acc[i][2] + bs[2], acc[i][3] + bs[3]);
      *(float4*)(G + m * G4H + jc) = v;
    }
  }
}

// ---------------------------------------------------------------------------
// Recurrence: one block (512 threads) per batch element, all state in LDS.
// Streaming GEMVs use explicit SW-pipelined double-buffered register loads.
// ---------------------------------------------------------------------------
__global__ __launch_bounds__(512, 2) void mann_kernel(
    const float* __restrict__ G,
    const float* __restrict__ WhhT,
    const float* __restrict__ WrhT,
    const float* __restrict__ WkaT,
    const float* __restrict__ bka,
    const float* __restrict__ brh,
    const float* __restrict__ Who, const float* __restrict__ bho,
    const float* __restrict__ Wro, const float* __restrict__ bro,
    float* __restrict__ out)
{
  __shared__ float M_s[NN * MST];
  __shared__ float h_s[HH], c_s[HH], brh_s[HH];
  __shared__ float r_s[RR * DD];
  __shared__ float wr_s[RR * NN], K_s[RR * NN], ww_s[RR * NN];
  __shared__ float wu_s[NN], Mn2_s[NN], kn2_s[RR];
  __shared__ __attribute__((aligned(16))) float gates_s[G4H];
  __shared__ __attribute__((aligned(16))) float ka_s[KAW];
  __shared__ __attribute__((aligned(16))) float bka_s[KAW];
  __shared__ __attribute__((aligned(16))) float Gbuf_s[2][G4H];
  __shared__ __attribute__((aligned(16))) float pka_s[KAW];
  __shared__ float pk_s[HH];
  __shared__ float Who_s[NCLS * HH], Wro_s[NCLS * RR * DD], bo_s[NCLS];
  __shared__ int   lu_s[RR];

  const int tid = threadIdx.x;
  const int b   = blockIdx.x;

  // ---- init ----
  for (int e = tid; e < NN * MST; e += 512) M_s[e] = 0.f;
  wr_s[tid] = 0.f;
  if (tid < NN) wu_s[tid] = 0.f;
  if (tid < HH) { h_s[tid] = 0.f; c_s[tid] = 0.f; brh_s[tid] = brh[tid]; }
  if (tid < RR * DD) r_s[tid] = 0.f;
  for (int e = tid; e < NCLS * HH; e += 512) Who_s[e] = Who[e];
  for (int e = tid; e < NCLS * RR * DD; e += 512) Wro_s[e] = Wro[e];
  if (tid < NCLS) bo_s[tid] = bho[tid] + bro[tid];
  if (tid < KAW) bka_s[tid] = bka[tid];
  if (tid >= 448) {  // prefetch G row for t=0
    const float4* Gr = (const float4*)(G + (size_t)b * TB * G4H);
    for (int i = tid - 448; i < 200; i += 64) *(float4*)&Gbuf_s[0][4 * i] = Gr[i];
  }
  __syncthreads();

#pragma clang loop unroll(disable)
  for (int t = 0; t < TB; ++t) {
    float p1_acc = 0.f;
    float2 p4_acc = make_float2(0.f, 0.f);

    // ---- P1: h += r @ Wrh^T + brh  (400 lanes: 200 outputs x 2 k-halves) ----
    if (tid < 400) {
      const int kh = (tid < 200) ? 0 : 1;
      const int j  = tid - kh * 200;
      const int kbeg = kh * 80;
      const float* W = WrhT + (size_t)kbeg * HH + j;
      float b0[8], b1[8];
      float acc = 0.f;
#pragma unroll
      for (int u = 0; u < 8; ++u) b0[u] = W[u * HH];
      for (int c = 1; c < 10; ++c) {
        const float* Wc = W + c * 8 * HH;
#pragma unroll
        for (int u = 0; u < 8; ++u) b1[u] = Wc[u * HH];
        const int kb = kbeg + (c - 1) * 8;
#pragma unroll
        for (int u = 0; u < 8; ++u) acc += r_s[kb + u] * b0[u];
#pragma unroll
        for (int u = 0; u < 8; ++u) b0[u] = b1[u];
      }
#pragma unroll
      for (int u = 0; u < 8; ++u) acc += r_s[kbeg + 72 + u] * b0[u];
      if (kh) pk_s[j] = acc;
      else    p1_acc = acc;
    }
    __syncthreads();
    if (tid < HH) h_s[tid] = h_s[tid] + brh_s[tid] + p1_acc + pk_s[tid];
    __syncthreads();

    // ---- P2: gates = Gbuf + h @ Whh^T  (400 lanes x float2) ----
    if (tid < 400) {
      const int j2 = tid;
      const float2* W = (const float2*)WhhT + j2;
      float2 acc = *(const float2*)&Gbuf_s[t & 1][2 * j2];
      float2 b0[8], b1[8];
#pragma unroll
      for (int u = 0; u < 8; ++u) b0[u] = W[u * 400];
      for (int c = 1; c < 25; ++c) {
        const float2* Wc = W + c * 8 * 400;
#pragma unroll
        for (int u = 0; u < 8; ++u) b1[u] = Wc[u * 400];
        const int kb = (c - 1) * 8;
#pragma unroll
        for (int u = 0; u < 8; ++u) {
          const float hk = h_s[kb + u];
          acc.x += hk * b0[u].x; acc.y += hk * b0[u].y;
        }
#pragma unroll
        for (int u = 0; u < 8; ++u) b0[u] = b1[u];
      }
#pragma unroll
      for (int u = 0; u < 8; ++u) {
        const float hk = h_s[192 + u];
        acc.x += hk * b0[u].x; acc.y += hk * b0[u].y;
      }
      *(float2*)&gates_s[2 * j2] = acc;
    }
    __syncthreads();

    // ---- P3: LSTM pointwise ----
    if (tid < HH) {
      const float ig = sigmoidf_(gates_s[tid]);
      const float fg = sigmoidf_(gates_s[HH + tid]);
      const float gg = tanhf(gates_s[2 * HH + tid]);
      const float og = sigmoidf_(gates_s[3 * HH + tid]);
      const float cn = fg * c_s[tid] + ig * gg;
      c_s[tid] = cn;
      h_s[tid] = og * tanhf(cn);
    }
    __syncthreads();

    // ---- P4: [key|add|sigma] = bka + h @ Wka^T  (324 lanes: 162 float2 x 2 k-halves) ----
    if (tid < 324) {
      const int kh = (tid < 162) ? 0 : 1;
      const int j2 = tid - kh * 162;
      const int kbeg = kh * 100;
      const float2* W = (const float2*)WkaT + (size_t)kbeg * 162 + j2;
      float2 b0[8], b1[8];
      float2 acc = make_float2(0.f, 0.f);
#pragma unroll
      for (int u = 0; u < 8; ++u) b0[u] = W[u * 162];
      for (int c = 1; c < 12; ++c) {
        const float2* Wc = W + c * 8 * 162;
#pragma unroll
        for (int u = 0; u < 8; ++u) b1[u] = Wc[u * 162];
        const int kb = kbeg + (c - 1) * 8;
#pragma unroll
        for (int u = 0; u < 8; ++u) {
          const float hk = h_s[kb + u];
          acc.x += hk * b0[u].x; acc.y += hk * b0[u].y;
        }
#pragma unroll
        for (int u = 0; u < 8; ++u) b0[u] = b1[u];
      }
      float2 r4[4];
#pragma unroll
      for (int u = 0; u < 4; ++u) r4[u] = W[(96 + u) * 162];
#pragma unroll
      for (int u = 0; u < 8; ++u) {
        const float hk = h_s[kbeg + 88 + u];
        acc.x += hk * b0[u].x; acc.y += hk * b0[u].y;
      }
#pragma unroll
      for (int u = 0; u < 4; ++u) {
        const float hk = h_s[kbeg + 96 + u];
        acc.x += hk * r4[u].x; acc.y += hk * r4[u].y;
      }
      if (kh) *(float2*)&pka_s[2 * j2] = acc;
      else    p4_acc = acc;
    }
    __syncthreads();
    if (tid < 162) {
      const float2 p = *(const float2*)&pka_s[2 * tid];
      const float2 bb = *(const float2*)&bka_s[2 * tid];
      float2 v;
      v.x = p4_acc.x + p.x + bb.x;
      v.y = p4_acc.y + p.y + bb.y;
      *(float2*)&ka_s[2 * tid] = v;
    }
    __syncthreads();

    // ---- P5: least-used select (wave0) + key norms + G prefetch (wave7) ----
    if (tid < 64) {
      const int l = tid;
      unsigned u0 = __float_as_uint(wu_s[l]);
      unsigned u1 = __float_as_uint(wu_s[l + 64]);
      if (u0 == 0x80000000u) u0 = 0u;
      if (u1 == 0x80000000u) u1 = 0u;
      u0 = (u0 & 0x80000000u) ? ~u0 : (u0 | 0x80000000u);
      u1 = (u1 & 0x80000000u) ? ~u1 : (u1 | 0x80000000u);
      unsigned long long k0 = ((unsigned long long)u0 << 32) | (unsigned)l;
      unsigned long long k1 = ((unsigned long long)u1 << 32) | (unsigned)(l + 64);
#pragma unroll
      for (int rsel = 0; rsel < RR; ++rsel) {
        unsigned long long mn = (k0 < k1) ? k0 : k1;
#pragma unroll
        for (int off = 32; off; off >>= 1) {
          const unsigned long long o = __shfl_xor(mn, off);
          if (o < mn) mn = o;
        }
        const int idx = (int)(mn & 0xFFFFFFFFull);
        if (l == 0) lu_s[rsel] = idx;
        if (idx == l)      k0 = ~0ull;
        if (idx == l + 64) k1 = ~0ull;
      }
    } else if (tid < 68) {
      const int q = tid - 64;
      float s = 0.f;
#pragma unroll 8
      for (int d = 0; d < DD; ++d) { const float v = ka_s[q * DD + d]; s += v * v; }
      kn2_s[q] = s;
    } else if (tid >= 448 && t + 1 < TB) {
      const float4* Gr = (const float4*)(G + ((size_t)b * TB + t + 1) * G4H);
      float* dst = Gbuf_s[(t + 1) & 1];
      for (int i = tid - 448; i < 200; i += 64) *(float4*)&dst[4 * i] = Gr[i];
    }
    __syncthreads();

    // ---- P6: ww = sigma*wr + (1-sigma)*wlu  (512 lanes, 1 elem each) ----
    {
      const float sg = ka_s[320];
      const int l0 = lu_s[0], l1 = lu_s[1], l2 = lu_s[2], l3 = lu_s[3];
      const int n = tid & (NN - 1);
      const float wlu = (n == l0 || n == l1 || n == l2 || n == l3) ? 1.f : 0.f;
      ww_s[tid] = sg * wr_s[tid] + (1.f - sg) * wlu;
    }
    __syncthreads();

    // ---- P7: M = M*wlu + ww^T @ add ----
    {
      const int l0 = lu_s[0], l1 = lu_s[1], l2 = lu_s[2], l3 = lu_s[3];
      for (int e = tid; e < NN * DD; e += 512) {
        const int n = e / DD, d = e - n * DD;
        const float wlu = (n == l0 || n == l1 || n == l2 || n == l3) ? 1.f : 0.f;
        float acc = M_s[n * MST + d] * wlu;
#pragma unroll
        for (int q = 0; q < RR; ++q) acc += ww_s[q * NN + n] * ka_s[160 + q * DD + d];
        M_s[n * MST + d] = acc;
      }
    }
    __syncthreads();

    // ---- P7b: M row norms ----
    if (tid < NN) {
      float s = 0.f;
#pragma unroll 8
      for (int d = 0; d < DD; ++d) { const float v = M_s[tid * MST + d]; s += v * v; }
      Mn2_s[tid] = s;
    }
    __syncthreads();

    // ---- P8: K = cosine(key, M)  (512 lanes, 1 elem each) ----
    {
      const int q = tid >> 7, n = tid & (NN - 1);
      float s = 0.f;
#pragma unroll 8
      for (int d = 0; d < DD; ++d) s += ka_s[q * DD + d] * M_s[n * MST + d];
      K_s[tid] = s / sqrtf(kn2_s[q] * Mn2_s[n] + 1e-6f);
    }
    __syncthreads();

    // ---- P9: softmax over N (4 waves) ----
    if (tid < 256) {
      const int w = tid >> 6, l = tid & 63;
      const float v0 = K_s[w * NN + l], v1 = K_s[w * NN + 64 + l];
      float mx = fmaxf(v0, v1);
#pragma unroll
      for (int off = 32; off; off >>= 1) mx = fmaxf(mx, __shfl_xor(mx, off));
      const float e0 = expf(v0 - mx), e1 = expf(v1 - mx);
      float s = e0 + e1;
#pragma unroll
      for (int off = 32; off; off >>= 1) s += __shfl_xor(s, off);
      const float inv = 1.f / s;
      K_s[w * NN + l]      = e0 * inv;
      K_s[w * NN + 64 + l] = e1 * inv;
    }
    __syncthreads();

    // ---- P10: r = wr_t @ M ;  P11: wu update ----
    if (tid < RR * DD) {
      const int q = tid / DD, d = tid - q * DD;
      float acc = 0.f;
#pragma unroll 8
      for (int n = 0; n < NN; ++n) acc += K_s[q * NN + n] * M_s[n * MST + d];
      r_s[tid] = acc;
    } else if (tid >= 256 && tid < 384) {
      const int n = tid - 256;
      float s = 0.95f * wu_s[n];
#pragma unroll
      for (int q = 0; q < RR; ++q) s += K_s[q * NN + n] + ww_s[q * NN + n];
      wu_s[n] = s;
    }
    __syncthreads();

    // ---- P12: out (wave0) ; wr <- wr_t (waves 1-3) ----
    if (tid < 64) {
      const int l = tid;
      const size_t ob = ((size_t)b * TB + t) * NCLS;
#pragma unroll
      for (int j = 0; j < NCLS; ++j) {
        float p = 0.f;
        for (int k = l; k < HH; k += 64)      p += h_s[k] * Who_s[j * HH + k];
        for (int m = l; m < RR * DD; m += 64) p += r_s[m] * Wro_s[j * (RR * DD) + m];
#pragma unroll
        for (int off = 32; off; off >>= 1) p += __shfl_xor(p, off);
        if (l == 0) out[ob + j] = p + bo_s[j];
      }
    } else if (tid < 256) {
      for (int e = tid - 64; e < RR * NN; e += 192) wr_s[e] = K_s[e];
    }
    __syncthreads();
  }
}

// ---------------------------------------------------------------------------
extern "C" void kernel_launch(void* const* d_in, const int* in_sizes, int n_in,
                              void* d_out, int out_size, void* d_ws, size_t ws_size,
                              hipStream_t stream) {
  const float* x    = (const float*)d_in[0];
  const float* Wkey = (const float*)d_in[1];
  const float* bkey = (const float*)d_in[2];
  const float* Wadd = (const float*)d_in[3];
  const float* badd = (const float*)d_in[4];
  const float* Wsig = (const float*)d_in[5];
  const float* bsig = (const float*)d_in[6];
  const float* Who  = (const float*)d_in[7];
  const float* bho  = (const float*)d_in[8];
  const float* Wro  = (const float*)d_in[9];
  const float* bro  = (const float*)d_in[10];
  const float* Wrh  = (const float*)d_in[11];
  const float* brh  = (const float*)d_in[12];
  const float* Wih  = (const float*)d_in[13];
  const float* bih  = (const float*)d_in[14];
  const float* Whh  = (const float*)d_in[15];
  const float* bhh  = (const float*)d_in[16];

  float* ws   = (float*)d_ws;
  float* G    = ws;                       // 25600*800
  float* WhhT = G + (size_t)25600 * 800;  // 160,000
  float* WrhT = WhhT + 160000;            // 32,000
  float* WkaT = WrhT + 32000;             // 64,800
  float* bka  = WkaT + 64800;             // 324

  prep_kernel<<<(160000 + 255) / 256, 256, 0, stream>>>(
      Whh, Wrh, Wkey, Wadd, Wsig, bkey, badd, bsig, WhhT, WrhT, WkaT, bka);

  dim3 gA((G4H + 63) / 64, 25600 / 64);
  gemm_in_kernel<<<gA, 256, 0, stream>>>(x, Wih, bih, bhh, G);

  mann_kernel<<<BB, 512, 0, stream>>>(G, WhhT, WrhT, WkaT, bka, brh,
                                      Who, bho, Wro, bro, (float*)d_out);
}

// Round 3
// 4574.780 us; speedup vs baseline: 4.8595x; 3.7077x over previous
//
#include <hip/hip_runtime.h>
#include <math.h>

// Problem dims
#define TB   100
#define BB   256
#define INF_ 784
#define HH   200
#define RR   4
#define NN   128
#define DD   40
#define NCLS 5
#define G4H  800   // 4*H
#define KAW  324   // 160 key + 160 add + 1 sigma + 3 pad
#define MST  44    // padded M row stride (multiple of 4; 11*16B units -> odd -> conflict-free b128)
#define NBAT 4     // batches per block
#define NBLK (BB / NBAT)

__device__ __forceinline__ float sigmoidf_(float x) { return 1.0f / (1.0f + expf(-x)); }

#define ADV(c, CC) { ++(c); if ((c) == (CC)) (c) = 0; }

// 4-slot rotating software pipeline: slots w0..w3 (declared by caller),
// LOADM(buf, chunk) issues loads, FMAM(buf, chunk) consumes. Keeps ~3-4
// chunks of loads in flight with no vmcnt(0) copy serialization.
#define PIPE4(CC, OFS, LOADM, FMAM)                                     \
  {                                                                     \
    int chL = (OFS), chF = (OFS);                                       \
    LOADM(w0, chL); ADV(chL, CC); LOADM(w1, chL); ADV(chL, CC);         \
    LOADM(w2, chL); ADV(chL, CC);                                       \
    _Pragma("unroll 1")                                                 \
    for (int g = 0; g < ((CC) - 3) / 4; ++g) {                          \
      LOADM(w3, chL); ADV(chL, CC); FMAM(w0, chF); ADV(chF, CC);        \
      LOADM(w0, chL); ADV(chL, CC); FMAM(w1, chF); ADV(chF, CC);        \
      LOADM(w1, chL); ADV(chL, CC); FMAM(w2, chF); ADV(chF, CC);        \
      LOADM(w2, chL); ADV(chL, CC); FMAM(w3, chF); ADV(chF, CC);        \
    }                                                                   \
    {                                                                   \
      constexpr int REMX = (CC) - 3 - 4 * (((CC) - 3) / 4);             \
      if (REMX >= 1) { LOADM(w3, chL); ADV(chL, CC); }                  \
      FMAM(w0, chF); ADV(chF, CC);                                      \
      if (REMX >= 2) { LOADM(w0, chL); ADV(chL, CC); }                  \
      FMAM(w1, chF); ADV(chF, CC);                                      \
      if (REMX >= 3) { LOADM(w1, chL); ADV(chL, CC); }                  \
      FMAM(w2, chF); ADV(chF, CC);                                      \
      if (REMX >= 1) { FMAM(w3, chF); ADV(chF, CC); }                   \
      if (REMX >= 2) { FMAM(w0, chF); ADV(chF, CC); }                   \
      if (REMX >= 3) { FMAM(w1, chF); ADV(chF, CC); }                   \
    }                                                                   \
  }

// ---------------------------------------------------------------------------
// Prep: transpose weights into GEMV-friendly (k-major) layouts in workspace.
// ---------------------------------------------------------------------------
__global__ __launch_bounds__(256) void prep_kernel(
    const float* __restrict__ Whh, const float* __restrict__ Wrh,
    const float* __restrict__ Wkey, const float* __restrict__ Wadd,
    const float* __restrict__ Wsig, const float* __restrict__ bkey,
    const float* __restrict__ badd, const float* __restrict__ bsig,
    float* __restrict__ WhhT, float* __restrict__ WrhT,
    float* __restrict__ WkaT, float* __restrict__ bka)
{
  const int tid = blockIdx.x * 256 + threadIdx.x;
  if (tid < 160000) {            // Whh (800,200) -> WhhT (200,800)
    const int j = tid / 200, k = tid - j * 200;
    WhhT[k * G4H + j] = Whh[tid];
  }
  if (tid < 32000) {             // Wrh (200,160) -> WrhT (160,200)
    const int k = tid / 160, m = tid - k * 160;
    WrhT[m * HH + k] = Wrh[tid];
  }
  if (tid < 200 * KAW) {         // [Wkey(160,200)|Wadd(160,200)|Wsig(1,200)]^T
    const int k = tid / KAW, j = tid - k * KAW;
    float v = 0.0f;
    if (j < 160)       v = Wkey[j * HH + k];
    else if (j < 320)  v = Wadd[(j - 160) * HH + k];
    else if (j == 320) v = Wsig[k];
    WkaT[tid] = v;
  }
  if (tid < KAW) {
    float v = 0.0f;
    if (tid < 160)       v = bkey[tid];
    else if (tid < 320)  v = badd[tid - 160];
    else if (tid == 320) v = bsig[0];
    bka[tid] = v;
  }
}

// ---------------------------------------------------------------------------
// Big GEMM: G[m, j] = sum_k x[m,k]*Wih[j,k] + bih[j] + bhh[j]
// ---------------------------------------------------------------------------
__global__ __launch_bounds__(256) void gemm_in_kernel(
    const float* __restrict__ X, const float* __restrict__ Wih,
    const float* __restrict__ bih, const float* __restrict__ bhh,
    float* __restrict__ G)
{
  __shared__ float As[16 * 68];
  __shared__ float Bs[16 * 68];
  const int tid  = threadIdx.x;
  const int tx   = tid & 15, ty = tid >> 4;
  const int lrow = tid >> 2, lk = (tid & 3) * 4;
  const int n0 = blockIdx.x * 64;
  const int m0 = blockIdx.y * 64;
  const int jg = n0 + lrow;
  const float* Xp = X   + (size_t)(m0 + lrow) * INF_ + lk;
  const float* Wp = Wih + (size_t)jg * INF_ + lk;

  float acc[4][4];
#pragma unroll
  for (int i = 0; i < 4; ++i)
#pragma unroll
    for (int j = 0; j < 4; ++j) acc[i][j] = 0.f;

  for (int k0 = 0; k0 < INF_; k0 += 16) {
    const float4 a = *(const float4*)(Xp + k0);
    const float4 b = (jg < G4H) ? *(const float4*)(Wp + k0)
                                : make_float4(0.f, 0.f, 0.f, 0.f);
    __syncthreads();
    const float av[4] = {a.x, a.y, a.z, a.w};
    const float bv[4] = {b.x, b.y, b.z, b.w};
#pragma unroll
    for (int u = 0; u < 4; ++u) {
      As[(lk + u) * 68 + lrow] = av[u];
      Bs[(lk + u) * 68 + lrow] = bv[u];
    }
    __syncthreads();
#pragma unroll
    for (int k = 0; k < 16; ++k) {
      const float4 a4 = *(const float4*)&As[k * 68 + ty * 4];
      const float4 b4 = *(const float4*)&Bs[k * 68 + tx * 4];
      const float aa[4] = {a4.x, a4.y, a4.z, a4.w};
      const float bb[4] = {b4.x, b4.y, b4.z, b4.w};
#pragma unroll
      for (int i = 0; i < 4; ++i)
#pragma unroll
        for (int j = 0; j < 4; ++j) acc[i][j] += aa[i] * bb[j];
    }
  }
  const int jc = n0 + tx * 4;
  if (jc < G4H) {
    float bs[4];
#pragma unroll
    for (int u = 0; u < 4; ++u) bs[u] = bih[jc + u] + bhh[jc + u];
#pragma unroll
    for (int i = 0; i < 4; ++i) {
      const size_t m = (size_t)m0 + ty * 4 + i;
      const float4 v = make_float4(acc[i][0] + bs[0], acc[i][1] + bs[1],
                                   acc[i][2] + bs[2], acc[i][3] + bs[3]);
      *(float4*)(G + m * G4H + jc) = v;
    }
  }
}

// ---------------------------------------------------------------------------
// Recurrence: one block (512 thr) per 4 batch elements; weights streamed once
// per step per block serve 4 GEMVs; k-order skewed per block.
// ---------------------------------------------------------------------------
__global__ __launch_bounds__(512, 2) void mann_kernel(
    const float* __restrict__ G, const float* __restrict__ WhhT,
    const float* __restrict__ WrhT, const float* __restrict__ WkaT,
    const float* __restrict__ bka, const float* __restrict__ brh,
    const float* __restrict__ Who, const float* __restrict__ bho,
    const float* __restrict__ Wro, const float* __restrict__ bro,
    float* __restrict__ out)
{
  __shared__ __attribute__((aligned(16))) float M_s[NBAT][NN * MST]; // 90112 B
  __shared__ __attribute__((aligned(16))) float h4[HH * 4];          // batch-interleaved
  __shared__ __attribute__((aligned(16))) float c4[HH * 4];
  __shared__ __attribute__((aligned(16))) float r4[RR * DD * 4];
  __shared__ float brh_s[HH];
  __shared__ float wr_s[NBAT][RR * NN];
  __shared__ float ww_s[NBAT][RR * NN];
  __shared__ float wu_s[NBAT][NN];
  __shared__ float Mn2_s[NBAT][NN];
  __shared__ float kn2_s[NBAT][RR];
  __shared__ __attribute__((aligned(16))) float gates_s[NBAT][G4H];
  __shared__ __attribute__((aligned(16))) float ka_s[NBAT][KAW];
  __shared__ __attribute__((aligned(16))) float bka_s[KAW];
  __shared__ __attribute__((aligned(16))) float Gbuf_s[NBAT][G4H];
  __shared__ float Who_s[NCLS * HH], Wro_s[NCLS * RR * DD], bo_s[NCLS];
  __shared__ int   lu_s[NBAT][RR];

  // Aliases (temporally disjoint uses of the gates region):
  float* Kp  = &gates_s[0][0];          // [4][512] wr_t, written P8, dead after P12
  float* pk4 = &gates_s[0][0];          // float4[200] P1 partials (pre-P2)
  float* pka = &gates_s[0][0] + 1904;   // [4][324] P4 partials (post-P3, pre-P8)

  const int tid = threadIdx.x;
  const int b0  = blockIdx.x * NBAT;

  // ---- init ----
  for (int e = tid; e < NBAT * NN * MST; e += 512) (&M_s[0][0])[e] = 0.f;
  if (tid < NBAT * NN) { (&wu_s[0][0])[tid] = 0.f; (&wr_s[0][0])[tid] = 0.f; }
  if (tid < NBAT * NN) (&wr_s[0][0])[tid + 512 < NBAT * RR * NN ? 0 : 0] = (&wr_s[0][0])[0]; // no-op guard
  for (int e = tid; e < NBAT * RR * NN; e += 512) (&wr_s[0][0])[e] = 0.f;
  for (int e = tid; e < HH * 4; e += 512) { h4[e] = 0.f; c4[e] = 0.f; }
  for (int e = tid; e < RR * DD * 4; e += 512) r4[e] = 0.f;
  if (tid < HH) brh_s[tid] = brh[tid];
  if (tid < KAW) bka_s[tid] = bka[tid];
  for (int e = tid; e < NCLS * HH; e += 512) Who_s[e] = Who[e];
  for (int e = tid; e < NCLS * RR * DD; e += 512) Wro_s[e] = Wro[e];
  if (tid < NCLS) bo_s[tid] = bho[tid] + bro[tid];
  for (int idx = tid; idx < NBAT * 200; idx += 512) {
    const int i = idx / 200, o = idx - i * 200;
    ((float4*)&Gbuf_s[i][0])[o] =
        ((const float4*)(G + ((size_t)(b0 + i) * TB) * G4H))[o];
  }
  __syncthreads();

  const int ofs1 = (int)((blockIdx.x * 3u) % 10u);
  const int ofs2 = (int)((blockIdx.x * 7u) % 25u);
  const int ofs4 = (int)((blockIdx.x * 5u) % 12u);

#pragma clang loop unroll(disable)
  for (int t = 0; t < TB; ++t) {
    // ---- P1: h += r @ Wrh^T + brh (400 lanes: 200 outs x 2 k-halves, 4 bat) ----
    float a0 = 0.f, a1 = 0.f, a2 = 0.f, a3 = 0.f;
    if (tid < 400) {
      const int kh   = (tid < 200) ? 0 : 1;
      const int j    = tid - kh * 200;
      const int kbeg = kh * 80;
      const float* __restrict__ Wr = WrhT + (size_t)kbeg * HH + j;
      float w0[8], w1[8], w2[8], w3[8];
#define P1_LOAD(B, CH) { const int mm = (CH) * 8; _Pragma("unroll") \
      for (int u = 0; u < 8; ++u) B[u] = Wr[(mm + u) * HH]; }
#define P1_FMA(B, CH) { const int kb = (kbeg + (CH) * 8) * 4; _Pragma("unroll") \
      for (int u = 0; u < 8; ++u) { const float4 rk = *(const float4*)&r4[kb + u * 4]; \
        a0 += rk.x * B[u]; a1 += rk.y * B[u]; a2 += rk.z * B[u]; a3 += rk.w * B[u]; } }
      PIPE4(10, ofs1, P1_LOAD, P1_FMA)
      if (kh) *(float4*)&pk4[4 * j] = make_float4(a0, a1, a2, a3);
    }
    __syncthreads();
    if (tid < 200) {
      const float4 p = *(const float4*)&pk4[4 * tid];
      float4 hv = *(const float4*)&h4[4 * tid];
      const float br = brh_s[tid];
      hv.x += br + a0 + p.x; hv.y += br + a1 + p.y;
      hv.z += br + a2 + p.z; hv.w += br + a3 + p.w;
      *(float4*)&h4[4 * tid] = hv;
    }
    __syncthreads();

    // ---- P2: gates = Gbuf + h @ Whh^T (400 lanes x float2, 4 batches) ----
    if (tid < 400) {
      const float2* __restrict__ Wh = (const float2*)WhhT + tid;
      float2 g0 = *(const float2*)&Gbuf_s[0][2 * tid];
      float2 g1 = *(const float2*)&Gbuf_s[1][2 * tid];
      float2 g2 = *(const float2*)&Gbuf_s[2][2 * tid];
      float2 g3 = *(const float2*)&Gbuf_s[3][2 * tid];
      float2 w0[8], w1[8], w2[8], w3[8];
#define P2_LOAD(B, CH) { const int kk = (CH) * 8; _Pragma("unroll") \
      for (int u = 0; u < 8; ++u) B[u] = Wh[(kk + u) * 400]; }
#define P2_FMA(B, CH) { const int kc = (CH) * 32; _Pragma("unroll") \
      for (int u = 0; u < 8; ++u) { const float4 hk = *(const float4*)&h4[kc + u * 4]; \
        g0.x += hk.x * B[u].x; g0.y += hk.x * B[u].y; \
        g1.x += hk.y * B[u].x; g1.y += hk.y * B[u].y; \
        g2.x += hk.z * B[u].x; g2.y += hk.z * B[u].y; \
        g3.x += hk.w * B[u].x; g3.y += hk.w * B[u].y; } }
      PIPE4(25, ofs2, P2_LOAD, P2_FMA)
      *(float2*)&gates_s[0][2 * tid] = g0;
      *(float2*)&gates_s[1][2 * tid] = g1;
      *(float2*)&gates_s[2][2 * tid] = g2;
      *(float2*)&gates_s[3][2 * tid] = g3;
    }
    __syncthreads();

    // ---- P3: LSTM pointwise (800 items) ----
    for (int e = tid; e < NBAT * HH; e += 512) {
      const int i = e / HH, k = e - i * HH;
      const float ig = sigmoidf_(gates_s[i][k]);
      const float fg = sigmoidf_(gates_s[i][HH + k]);
      const float gg = tanhf(gates_s[i][2 * HH + k]);
      const float og = sigmoidf_(gates_s[i][3 * HH + k]);
      const float cn = fg * c4[k * 4 + i] + ig * gg;
      c4[k * 4 + i] = cn;
      h4[k * 4 + i] = og * tanhf(cn);
    }
    __syncthreads();

    // ---- P4: [key|add|sigma] = bka + h @ Wka^T ; waves 6-7 prefetch G(t+1) ----
    float2 ka0 = {0.f, 0.f}, ka1 = {0.f, 0.f}, ka2 = {0.f, 0.f}, ka3 = {0.f, 0.f};
    if (tid < 324) {
      const int kh = (tid < 162) ? 0 : 1;
      const int j2 = tid - kh * 162;
      const int kbeg = kh * 100;
      const float2* __restrict__ Wk = (const float2*)WkaT + (size_t)kbeg * 162 + j2;
      float2 w0[8], w1[8], w2[8], w3[8];
#define P4_LOAD(B, CH) { const int kk = (CH) * 8; _Pragma("unroll") \
      for (int u = 0; u < 8; ++u) B[u] = Wk[(kk + u) * 162]; }
#define P4_FMA(B, CH) { const int kc = (kbeg + (CH) * 8) * 4; _Pragma("unroll") \
      for (int u = 0; u < 8; ++u) { const float4 hk = *(const float4*)&h4[kc + u * 4]; \
        ka0.x += hk.x * B[u].x; ka0.y += hk.x * B[u].y; \
        ka1.x += hk.y * B[u].x; ka1.y += hk.y * B[u].y; \
        ka2.x += hk.z * B[u].x; ka2.y += hk.z * B[u].y; \
        ka3.x += hk.w * B[u].x; ka3.y += hk.w * B[u].y; } }
      PIPE4(12, ofs4, P4_LOAD, P4_FMA)
      {  // tail k = kbeg+96..99
        float2 wt[4];
#pragma unroll
        for (int u = 0; u < 4; ++u) wt[u] = Wk[(96 + u) * 162];
#pragma unroll
        for (int u = 0; u < 4; ++u) {
          const float4 hk = *(const float4*)&h4[(kbeg + 96 + u) * 4];
          ka0.x += hk.x * wt[u].x; ka0.y += hk.x * wt[u].y;
          ka1.x += hk.y * wt[u].x; ka1.y += hk.y * wt[u].y;
          ka2.x += hk.z * wt[u].x; ka2.y += hk.z * wt[u].y;
          ka3.x += hk.w * wt[u].x; ka3.y += hk.w * wt[u].y;
        }
      }
      if (kh) {
        *(float2*)&pka[0 * KAW + 2 * j2] = ka0;
        *(float2*)&pka[1 * KAW + 2 * j2] = ka1;
        *(float2*)&pka[2 * KAW + 2 * j2] = ka2;
        *(float2*)&pka[3 * KAW + 2 * j2] = ka3;
      }
    } else if (tid >= 384 && t + 1 < TB) {
      for (int idx = tid - 384; idx < NBAT * 200; idx += 128) {
        const int i = idx / 200, o = idx - i * 200;
        ((float4*)&Gbuf_s[i][0])[o] =
            ((const float4*)(G + ((size_t)(b0 + i) * TB + t + 1) * G4H))[o];
      }
    }
    __syncthreads();
    if (tid < 162) {
      const float2 bb = *(const float2*)&bka_s[2 * tid];
      float2 p, v;
      p = *(const float2*)&pka[0 * KAW + 2 * tid];
      v.x = ka0.x + p.x + bb.x; v.y = ka0.y + p.y + bb.y;
      *(float2*)&ka_s[0][2 * tid] = v;
      p = *(const float2*)&pka[1 * KAW + 2 * tid];
      v.x = ka1.x + p.x + bb.x; v.y = ka1.y + p.y + bb.y;
      *(float2*)&ka_s[1][2 * tid] = v;
      p = *(const float2*)&pka[2 * KAW + 2 * tid];
      v.x = ka2.x + p.x + bb.x; v.y = ka2.y + p.y + bb.y;
      *(float2*)&ka_s[2][2 * tid] = v;
      p = *(const float2*)&pka[3 * KAW + 2 * tid];
      v.x = ka3.x + p.x + bb.x; v.y = ka3.y + p.y + bb.y;
      *(float2*)&ka_s[3][2 * tid] = v;
    }
    __syncthreads();

    // ---- P5: least-used select (waves 0-3, one per batch) + key norms ----
    if (tid < 256) {
      const int i = tid >> 6, l = tid & 63;
      unsigned u0v = __float_as_uint(wu_s[i][l]);
      unsigned u1v = __float_as_uint(wu_s[i][l + 64]);
      if (u0v == 0x80000000u) u0v = 0u;
      if (u1v == 0x80000000u) u1v = 0u;
      u0v = (u0v & 0x80000000u) ? ~u0v : (u0v | 0x80000000u);
      u1v = (u1v & 0x80000000u) ? ~u1v : (u1v | 0x80000000u);
      unsigned long long k0 = ((unsigned long long)u0v << 32) | (unsigned)l;
      unsigned long long k1 = ((unsigned long long)u1v << 32) | (unsigned)(l + 64);
#pragma unroll
      for (int rsel = 0; rsel < RR; ++rsel) {
        unsigned long long mn = (k0 < k1) ? k0 : k1;
#pragma unroll
        for (int off = 32; off; off >>= 1) {
          const unsigned long long o = __shfl_xor(mn, off);
          if (o < mn) mn = o;
        }
        const int idx = (int)(mn & 0xFFFFFFFFull);
        if (l == 0) lu_s[i][rsel] = idx;
        if (idx == l)      k0 = ~0ull;
        if (idx == l + 64) k1 = ~0ull;
      }
    } else if (tid < 272) {
      const int q = (tid - 256) & 3, i = (tid - 256) >> 2;
      float s = 0.f;
#pragma unroll
      for (int d4 = 0; d4 < 10; ++d4) {
        const float4 v = *(const float4*)&ka_s[i][q * DD + 4 * d4];
        s += v.x * v.x + v.y * v.y + v.z * v.z + v.w * v.w;
      }
      kn2_s[i][q] = s;
    }
    __syncthreads();

    // ---- P6: ww = sigma*wr + (1-sigma)*wlu ----
#pragma unroll
    for (int i = 0; i < NBAT; ++i) {
      const float sg = ka_s[i][320];
      const int l0 = lu_s[i][0], l1 = lu_s[i][1], l2 = lu_s[i][2], l3 = lu_s[i][3];
      const int n = tid & (NN - 1);
      const float wlu = (n == l0 || n == l1 || n == l2 || n == l3) ? 1.f : 0.f;
      ww_s[i][tid] = sg * wr_s[i][tid] + (1.f - sg) * wlu;
    }
    __syncthreads();

    // ---- P7: M = M*wlu + ww^T @ add ; fused row-norm Mn2 (lane = (i,n)) ----
    {
      const int i = tid >> 7, n = tid & (NN - 1);
      const int l0 = lu_s[i][0], l1 = lu_s[i][1], l2 = lu_s[i][2], l3 = lu_s[i][3];
      const float wlu = (n == l0 || n == l1 || n == l2 || n == l3) ? 1.f : 0.f;
      const float wwv0 = ww_s[i][n],          wwv1 = ww_s[i][NN + n];
      const float wwv2 = ww_s[i][2 * NN + n], wwv3 = ww_s[i][3 * NN + n];
      float* Mr = &M_s[i][n * MST];
      const float* Ad = &ka_s[i][160];
      float mn2 = 0.f;
#pragma unroll
      for (int d4 = 0; d4 < 10; ++d4) {
        float4 m = *(const float4*)&Mr[4 * d4];
        m.x *= wlu; m.y *= wlu; m.z *= wlu; m.w *= wlu;
        const float4 av0 = *(const float4*)&Ad[0 * DD + 4 * d4];
        const float4 av1 = *(const float4*)&Ad[1 * DD + 4 * d4];
        const float4 av2 = *(const float4*)&Ad[2 * DD + 4 * d4];
        const float4 av3 = *(const float4*)&Ad[3 * DD + 4 * d4];
        m.x += wwv0 * av0.x + wwv1 * av1.x + wwv2 * av2.x + wwv3 * av3.x;
        m.y += wwv0 * av0.y + wwv1 * av1.y + wwv2 * av2.y + wwv3 * av3.y;
        m.z += wwv0 * av0.z + wwv1 * av1.z + wwv2 * av2.z + wwv3 * av3.z;
        m.w += wwv0 * av0.w + wwv1 * av1.w + wwv2 * av2.w + wwv3 * av3.w;
        *(float4*)&Mr[4 * d4] = m;
        mn2 += m.x * m.x + m.y * m.y + m.z * m.z + m.w * m.w;
      }
      Mn2_s[i][n] = mn2;
    }
    __syncthreads();

    // ---- P8: K = cosine(key, M) -> Kp ----
#pragma unroll
    for (int ii = 0; ii < NBAT; ++ii) {
      const int q = tid >> 7, n = tid & (NN - 1);
      const float* Ky = &ka_s[ii][q * DD];
      const float* Mr = &M_s[ii][n * MST];
      float s = 0.f;
#pragma unroll
      for (int d4 = 0; d4 < 10; ++d4) {
        const float4 kv = *(const float4*)&Ky[4 * d4];
        const float4 mv = *(const float4*)&Mr[4 * d4];
        s += kv.x * mv.x + kv.y * mv.y + kv.z * mv.z + kv.w * mv.w;
      }
      Kp[(ii << 9) + tid] = s / sqrtf(kn2_s[ii][q] * Mn2_s[ii][n] + 1e-6f);
    }
    __syncthreads();

    // ---- P9: softmax over N (16 rows, 2 per wave) ----
    {
      const int w = tid >> 6, l = tid & 63;
#pragma unroll
      for (int rr = 0; rr < 2; ++rr) {
        float* Kr = Kp + (w * 2 + rr) * NN;
        const float v0 = Kr[l], v1 = Kr[l + 64];
        float mx = fmaxf(v0, v1);
#pragma unroll
        for (int off = 32; off; off >>= 1) mx = fmaxf(mx, __shfl_xor(mx, off));
        const float e0 = expf(v0 - mx), e1 = expf(v1 - mx);
        float s = e0 + e1;
#pragma unroll
        for (int off = 32; off; off >>= 1) s += __shfl_xor(s, off);
        const float inv = 1.f / s;
        Kr[l] = e0 * inv; Kr[l + 64] = e1 * inv;
      }
    }
    __syncthreads();

    // ---- P10: r = wr_t @ M (lanes<160) ; P11: wu update (lanes 256-511) ----
    if (tid < 160) {
      const int i = tid / 40, rem = tid - i * 40;
      const int q = rem / 10, d4 = rem - q * 10;
      const float* Kr = Kp + ((i << 2) + q) * NN;
      const float* Mb = &M_s[i][4 * d4];
      float4 acc = make_float4(0.f, 0.f, 0.f, 0.f);
      for (int s = 0; s < NN; ++s) {
        const int n = (s + tid) & (NN - 1);   // rotated to spread LDS banks
        const float kw = Kr[n];
        const float4 mv = *(const float4*)&Mb[n * MST];
        acc.x += kw * mv.x; acc.y += kw * mv.y;
        acc.z += kw * mv.z; acc.w += kw * mv.w;
      }
      const int dbase = (q * DD + 4 * d4) * 4 + i;
      r4[dbase]      = acc.x;
      r4[dbase + 4]  = acc.y;
      r4[dbase + 8]  = acc.z;
      r4[dbase + 12] = acc.w;
    } else if (tid >= 256) {
      const int e2 = tid - 256;
#pragma unroll
      for (int jj = 0; jj < 2; ++jj) {
        const int item = e2 + (jj << 8);
        const int i = item >> 7, n = item & (NN - 1);
        float s = 0.95f * wu_s[i][n];
#pragma unroll
        for (int q = 0; q < RR; ++q)
          s += Kp[(i << 9) + q * NN + n] + ww_s[i][q * NN + n];
        wu_s[i][n] = s;
      }
    }
    __syncthreads();

    // ---- P12: out (waves 0-3, one per batch) ; wr <- wr_t (waves 4-7) ----
    if (tid < 256) {
      const int i = tid >> 6, l = tid & 63;
      const size_t ob = ((size_t)(b0 + i) * TB + t) * NCLS;
#pragma unroll
      for (int j = 0; j < NCLS; ++j) {
        float p = 0.f;
        for (int k = l; k < HH; k += 64)      p += h4[k * 4 + i] * Who_s[j * HH + k];
        for (int m = l; m < RR * DD; m += 64) p += r4[m * 4 + i] * Wro_s[j * RR * DD + m];
#pragma unroll
        for (int off = 32; off; off >>= 1) p += __shfl_xor(p, off);
        if (l == 0) out[ob + j] = p + bo_s[j];
      }
    } else {
      for (int f = tid - 256; f < NBAT * RR * NN; f += 256) (&wr_s[0][0])[f] = Kp[f];
    }
    __syncthreads();
  }
}

// ---------------------------------------------------------------------------
extern "C" void kernel_launch(void* const* d_in, const int* in_sizes, int n_in,
                              void* d_out, int out_size, void* d_ws, size_t ws_size,
                              hipStream_t stream) {
  const float* x    = (const float*)d_in[0];
  const float* Wkey = (const float*)d_in[1];
  const float* bkey = (const float*)d_in[2];
  const float* Wadd = (const float*)d_in[3];
  const float* badd = (const float*)d_in[4];
  const float* Wsig = (const float*)d_in[5];
  const float* bsig = (const float*)d_in[6];
  const float* Who  = (const float*)d_in[7];
  const float* bho  = (const float*)d_in[8];
  const float* Wro  = (const float*)d_in[9];
  const float* bro  = (const float*)d_in[10];
  const float* Wrh  = (const float*)d_in[11];
  const float* brh  = (const float*)d_in[12];
  const float* Wih  = (const float*)d_in[13];
  const float* bih  = (const float*)d_in[14];
  const float* Whh  = (const float*)d_in[15];
  const float* bhh  = (const float*)d_in[16];

  float* ws   = (float*)d_ws;
  float* G    = ws;                       // 25600*800
  float* WhhT = G + (size_t)25600 * 800;  // 160,000
  float* WrhT = WhhT + 160000;            // 32,000
  float* WkaT = WrhT + 32000;             // 64,800
  float* bka  = WkaT + 64800;             // 324

  prep_kernel<<<(160000 + 255) / 256, 256, 0, stream>>>(
      Whh, Wrh, Wkey, Wadd, Wsig, bkey, badd, bsig, WhhT, WrhT, WkaT, bka);

  dim3 gA((G4H + 63) / 64, 25600 / 64);
  gemm_in_kernel<<<gA, 256, 0, stream>>>(x, Wih, bih, bhh, G);

  mann_kernel<<<NBLK, 512, 0, stream>>>(G, WhhT, WrhT, WkaT, bka, brh,
                                        Who, bho, Wro, bro, (float*)d_out);
}

// Round 8
// 3883.614 us; speedup vs baseline: 5.7243x; 1.1780x over previous
//
// MANN/NTM forward — R8 (same as R6/R7 source; broker infra failed twice, resubmitting)
#include <hip/hip_runtime.h>
#include <math.h>

// Problem dims
#define TB   100
#define BB   256
#define INF_ 784
#define HH   200
#define RR   4
#define NN   128
#define DD   40
#define NCLS 5
#define G4H  800   // 4*H
#define KAW  324   // 160 key + 160 add + 1 sigma + 3 pad
#define MST  44    // padded M row stride: stride-44 b128 over consecutive n hits the bank floor
#define NBAT 2     // batches per block
#define NBLK (BB / NBAT)

__device__ __forceinline__ float sigmoidf_(float x) { return 1.0f / (1.0f + expf(-x)); }

#define ADV(c, CC) { ++(c); if ((c) == (CC)) (c) = 0; }

// 4-slot rotating software pipeline (3 chunks of loads in flight ahead of FMA).
#define PIPE4(CC, OFS, LOADM, FMAM)                                     \
  {                                                                     \
    int chL = (OFS), chF = (OFS);                                       \
    LOADM(w0, chL); ADV(chL, CC); LOADM(w1, chL); ADV(chL, CC);         \
    LOADM(w2, chL); ADV(chL, CC);                                       \
    _Pragma("unroll 1")                                                 \
    for (int g = 0; g < ((CC) - 3) / 4; ++g) {                          \
      LOADM(w3, chL); ADV(chL, CC); FMAM(w0, chF); ADV(chF, CC);        \
      LOADM(w0, chL); ADV(chL, CC); FMAM(w1, chF); ADV(chF, CC);        \
      LOADM(w1, chL); ADV(chL, CC); FMAM(w2, chF); ADV(chF, CC);        \
      LOADM(w2, chL); ADV(chL, CC); FMAM(w3, chF); ADV(chF, CC);        \
    }                                                                   \
    {                                                                   \
      constexpr int REMX = (CC) - 3 - 4 * (((CC) - 3) / 4);             \
      if (REMX >= 1) { LOADM(w3, chL); ADV(chL, CC); }                  \
      FMAM(w0, chF); ADV(chF, CC);                                      \
      if (REMX >= 2) { LOADM(w0, chL); ADV(chL, CC); }                  \
      FMAM(w1, chF); ADV(chF, CC);                                      \
      if (REMX >= 3) { LOADM(w1, chL); ADV(chL, CC); }                  \
      FMAM(w2, chF); ADV(chF, CC);                                      \
      if (REMX >= 1) { FMAM(w3, chF); ADV(chF, CC); }                   \
      if (REMX >= 2) { FMAM(w0, chF); ADV(chF, CC); }                   \
      if (REMX >= 3) { FMAM(w1, chF); ADV(chF, CC); }                   \
    }                                                                   \
  }

// ---------------------------------------------------------------------------
// Prep: transpose weights into GEMV-friendly (k-major) layouts in workspace.
// ---------------------------------------------------------------------------
__global__ __launch_bounds__(256) void prep_kernel(
    const float* __restrict__ Whh, const float* __restrict__ Wrh,
    const float* __restrict__ Wkey, const float* __restrict__ Wadd,
    const float* __restrict__ Wsig, const float* __restrict__ bkey,
    const float* __restrict__ badd, const float* __restrict__ bsig,
    float* __restrict__ WhhT, float* __restrict__ WrhT,
    float* __restrict__ WkaT, float* __restrict__ bka)
{
  const int tid = blockIdx.x * 256 + threadIdx.x;
  if (tid < 160000) {            // Whh (800,200) -> WhhT (200,800)
    const int j = tid / 200, k = tid - j * 200;
    WhhT[k * G4H + j] = Whh[tid];
  }
  if (tid < 32000) {             // Wrh (200,160) -> WrhT (160,200)
    const int k = tid / 160, m = tid - k * 160;
    WrhT[m * HH + k] = Wrh[tid];
  }
  if (tid < 200 * KAW) {         // [Wkey(160,200)|Wadd(160,200)|Wsig(1,200)]^T
    const int k = tid / KAW, j = tid - k * KAW;
    float v = 0.0f;
    if (j < 160)       v = Wkey[j * HH + k];
    else if (j < 320)  v = Wadd[(j - 160) * HH + k];
    else if (j == 320) v = Wsig[k];
    WkaT[tid] = v;
  }
  if (tid < KAW) {
    float v = 0.0f;
    if (tid < 160)       v = bkey[tid];
    else if (tid < 320)  v = badd[tid - 160];
    else if (tid == 320) v = bsig[0];
    bka[tid] = v;
  }
}

// ---------------------------------------------------------------------------
// Big GEMM: G[m, j] = sum_k x[m,k]*Wih[j,k] + bih[j] + bhh[j]
// ---------------------------------------------------------------------------
__global__ __launch_bounds__(256) void gemm_in_kernel(
    const float* __restrict__ X, const float* __restrict__ Wih,
    const float* __restrict__ bih, const float* __restrict__ bhh,
    float* __restrict__ G)
{
  __shared__ float As[16 * 68];
  __shared__ float Bs[16 * 68];
  const int tid  = threadIdx.x;
  const int tx   = tid & 15, ty = tid >> 4;
  const int lrow = tid >> 2, lk = (tid & 3) * 4;
  const int n0 = blockIdx.x * 64;
  const int m0 = blockIdx.y * 64;
  const int jg = n0 + lrow;
  const float* Xp = X   + (size_t)(m0 + lrow) * INF_ + lk;
  const float* Wp = Wih + (size_t)jg * INF_ + lk;

  float acc[4][4];
#pragma unroll
  for (int i = 0; i < 4; ++i)
#pragma unroll
    for (int j = 0; j < 4; ++j) acc[i][j] = 0.f;

  for (int k0 = 0; k0 < INF_; k0 += 16) {
    const float4 a = *(const float4*)(Xp + k0);
    const float4 b = (jg < G4H) ? *(const float4*)(Wp + k0)
                                : make_float4(0.f, 0.f, 0.f, 0.f);
    __syncthreads();
    const float av[4] = {a.x, a.y, a.z, a.w};
    const float bv[4] = {b.x, b.y, b.z, b.w};
#pragma unroll
    for (int u = 0; u < 4; ++u) {
      As[(lk + u) * 68 + lrow] = av[u];
      Bs[(lk + u) * 68 + lrow] = bv[u];
    }
    __syncthreads();
#pragma unroll
    for (int k = 0; k < 16; ++k) {
      const float4 a4 = *(const float4*)&As[k * 68 + ty * 4];
      const float4 b4 = *(const float4*)&Bs[k * 68 + tx * 4];
      const float aa[4] = {a4.x, a4.y, a4.z, a4.w};
      const float bb[4] = {b4.x, b4.y, b4.z, b4.w};
#pragma unroll
      for (int i = 0; i < 4; ++i)
#pragma unroll
        for (int j = 0; j < 4; ++j) acc[i][j] += aa[i] * bb[j];
    }
  }
  const int jc = n0 + tx * 4;
  if (jc < G4H) {
    float bs[4];
#pragma unroll
    for (int u = 0; u < 4; ++u) bs[u] = bih[jc + u] + bhh[jc + u];
#pragma unroll
    for (int i = 0; i < 4; ++i) {
      const size_t m = (size_t)m0 + ty * 4 + i;
      const float4 v = make_float4(acc[i][0] + bs[0], acc[i][1] + bs[1],
                                   acc[i][2] + bs[2], acc[i][3] + bs[3]);
      *(float4*)(G + m * G4H + jc) = v;
    }
  }
}

// ---------------------------------------------------------------------------
// Recurrence: one block (512 thr) per 2 batch elements; 128 blocks -> 128 CUs.
// ---------------------------------------------------------------------------
__global__ __launch_bounds__(512, 2) void mann_kernel(
    const float* __restrict__ G, const float* __restrict__ WhhT,
    const float* __restrict__ WrhT, const float* __restrict__ WkaT,
    const float* __restrict__ bka, const float* __restrict__ brh,
    const float* __restrict__ Who, const float* __restrict__ bho,
    const float* __restrict__ Wro, const float* __restrict__ bro,
    float* __restrict__ out)
{
  __shared__ __attribute__((aligned(16))) float M_s[NBAT][NN * MST]; // 45056 B
  __shared__ __attribute__((aligned(16))) float h2[HH * NBAT];       // batch-interleaved
  __shared__ __attribute__((aligned(16))) float c2[HH * NBAT];
  __shared__ __attribute__((aligned(16))) float r2[RR * DD * NBAT];
  __shared__ float brh_s[HH];
  __shared__ float wr_s[NBAT][RR * NN];
  __shared__ float ww_s[NBAT][RR * NN];
  __shared__ float wu_s[NBAT][NN];
  __shared__ float Mn2_s[NBAT][NN];
  __shared__ float kn2_s[NBAT][RR];
  __shared__ __attribute__((aligned(16))) float gates_s[NBAT][G4H];
  __shared__ __attribute__((aligned(16))) float ka_s[NBAT][KAW];
  __shared__ __attribute__((aligned(16))) float bka_s[KAW];
  __shared__ __attribute__((aligned(16))) float Gbuf_s[NBAT][G4H];
  __shared__ float Who_s[NCLS * HH], Wro_s[NCLS * RR * DD], bo_s[NCLS];
  __shared__ int   lu_s[NBAT][RR];

  // Aliases into the gates region (temporally disjoint):
  float* Kp  = &gates_s[0][0];          // [2][512] wr_t (written P8, dead after P12)
  float* pk2 = &gates_s[0][0];          // float2[200] P1 partials (pre-P2)
  float* pka = &gates_s[0][0] + 952;    // [2][324] P4 partials (post-P3, pre-combine)

  const int tid = threadIdx.x;
  const int b0  = blockIdx.x * NBAT;

  // ---- init ----
  for (int e = tid; e < NBAT * NN * MST; e += 512) (&M_s[0][0])[e] = 0.f;
  for (int e = tid; e < NBAT * RR * NN; e += 512) (&wr_s[0][0])[e] = 0.f;
  if (tid < NBAT * NN) (&wu_s[0][0])[tid] = 0.f;
  for (int e = tid; e < HH * NBAT; e += 512) { h2[e] = 0.f; c2[e] = 0.f; }
  if (tid < RR * DD * NBAT) r2[tid] = 0.f;
  if (tid < HH) brh_s[tid] = brh[tid];
  if (tid < KAW) bka_s[tid] = bka[tid];
  for (int e = tid; e < NCLS * HH; e += 512) Who_s[e] = Who[e];
  for (int e = tid; e < NCLS * RR * DD; e += 512) Wro_s[e] = Wro[e];
  if (tid < NCLS) bo_s[tid] = bho[tid] + bro[tid];
  if (tid < NBAT * 200) {
    const int i = tid / 200, o = tid - i * 200;
    ((float4*)&Gbuf_s[i][0])[o] =
        ((const float4*)(G + ((size_t)(b0 + i) * TB) * G4H))[o];
  }
  __syncthreads();

  const int ofs1 = (int)((blockIdx.x * 3u) % 10u);
  const int ofs2 = (int)((blockIdx.x * 7u) % 25u);
  const int ofs4 = (int)((blockIdx.x * 5u) % 12u);

#pragma clang loop unroll(disable)
  for (int t = 0; t < TB; ++t) {
    float a0 = 0.f, a1 = 0.f;

    // ---- P1: h += r @ Wrh^T + brh (400 lanes: 200 outs x 2 k-halves) ----
    if (tid < 400) {
      const int kh   = (tid < 200) ? 0 : 1;
      const int j    = tid - kh * 200;
      const int kbeg = kh * 80;
      const float* __restrict__ Wr = WrhT + (size_t)kbeg * HH + j;
      float w0[8], w1[8], w2[8], w3[8];
#define P1_LOAD(B, CH) { const int mm = (CH) * 8; _Pragma("unroll") \
      for (int u = 0; u < 8; ++u) B[u] = Wr[(mm + u) * HH]; }
#define P1_FMA(B, CH) { const int kb = (kbeg + (CH) * 8) * NBAT; _Pragma("unroll") \
      for (int u = 0; u < 8; ++u) { const float2 rk = *(const float2*)&r2[kb + u * NBAT]; \
        a0 += rk.x * B[u]; a1 += rk.y * B[u]; } }
      PIPE4(10, ofs1, P1_LOAD, P1_FMA)
      if (kh) *(float2*)&pk2[2 * j] = make_float2(a0, a1);
    }
    __syncthreads();
    if (tid < 200) {
      const float2 p = *(const float2*)&pk2[2 * tid];
      float2 hv = *(const float2*)&h2[2 * tid];
      const float br = brh_s[tid];
      hv.x += br + a0 + p.x; hv.y += br + a1 + p.y;
      *(float2*)&h2[2 * tid] = hv;
    }
    __syncthreads();

    // ---- P2: gates = Gbuf + h @ Whh^T (400 lanes x float2-col, 2 batches) ----
    if (tid < 400) {
      const float2* __restrict__ Wh = (const float2*)WhhT + tid;
      float2 g0 = *(const float2*)&Gbuf_s[0][2 * tid];
      float2 g1 = *(const float2*)&Gbuf_s[1][2 * tid];
      float2 w0[8], w1[8], w2[8], w3[8];
#define P2_LOAD(B, CH) { const int kk = (CH) * 8; _Pragma("unroll") \
      for (int u = 0; u < 8; ++u) B[u] = Wh[(kk + u) * 400]; }
#define P2_FMA(B, CH) { const int kc = (CH) * 8; _Pragma("unroll") \
      for (int u = 0; u < 8; ++u) { const float2 hk = *(const float2*)&h2[(kc + u) * NBAT]; \
        g0.x += hk.x * B[u].x; g0.y += hk.x * B[u].y; \
        g1.x += hk.y * B[u].x; g1.y += hk.y * B[u].y; } }
      PIPE4(25, ofs2, P2_LOAD, P2_FMA)
      *(float2*)&gates_s[0][2 * tid] = g0;
      *(float2*)&gates_s[1][2 * tid] = g1;
    }
    __syncthreads();

    // ---- P3: LSTM pointwise (400 items) ----
    if (tid < NBAT * HH) {
      const int i = tid / HH, k = tid - i * HH;
      const float ig = sigmoidf_(gates_s[i][k]);
      const float fg = sigmoidf_(gates_s[i][HH + k]);
      const float gg = tanhf(gates_s[i][2 * HH + k]);
      const float og = sigmoidf_(gates_s[i][3 * HH + k]);
      const float cn = fg * c2[k * NBAT + i] + ig * gg;
      c2[k * NBAT + i] = cn;
      h2[k * NBAT + i] = og * tanhf(cn);
    }
    __syncthreads();

    // ---- P4: [key|add|sigma] = bka + h @ Wka^T ; lanes>=384 prefetch G(t+1) ----
    float2 ka0 = {0.f, 0.f}, ka1 = {0.f, 0.f};
    if (tid < 324) {
      const int kh = (tid < 162) ? 0 : 1;
      const int j2 = tid - kh * 162;
      const int kbeg = kh * 100;
      const float2* __restrict__ Wk = (const float2*)WkaT + (size_t)kbeg * 162 + j2;
      float2 w0[8], w1[8], w2[8], w3[8];
#define P4_LOAD(B, CH) { const int kk = (CH) * 8; _Pragma("unroll") \
      for (int u = 0; u < 8; ++u) B[u] = Wk[(kk + u) * 162]; }
#define P4_FMA(B, CH) { const int kc = (kbeg + (CH) * 8) * NBAT; _Pragma("unroll") \
      for (int u = 0; u < 8; ++u) { const float2 hk = *(const float2*)&h2[kc + u * NBAT]; \
        ka0.x += hk.x * B[u].x; ka0.y += hk.x * B[u].y; \
        ka1.x += hk.y * B[u].x; ka1.y += hk.y * B[u].y; } }
      PIPE4(12, ofs4, P4_LOAD, P4_FMA)
      {  // tail k = kbeg+96..99
        float2 wt[4];
#pragma unroll
        for (int u = 0; u < 4; ++u) wt[u] = Wk[(96 + u) * 162];
#pragma unroll
        for (int u = 0; u < 4; ++u) {
          const float2 hk = *(const float2*)&h2[(kbeg + 96 + u) * NBAT];
          ka0.x += hk.x * wt[u].x; ka0.y += hk.x * wt[u].y;
          ka1.x += hk.y * wt[u].x; ka1.y += hk.y * wt[u].y;
        }
      }
      if (kh) {
        *(float2*)&pka[0 * KAW + 2 * j2] = ka0;
        *(float2*)&pka[1 * KAW + 2 * j2] = ka1;
      }
    } else if (tid >= 384 && t + 1 < TB) {
      for (int idx = tid - 384; idx < NBAT * 200; idx += 128) {   // full 400-float4 refresh
        const int i = idx / 200, o = idx - i * 200;
        ((float4*)&Gbuf_s[i][0])[o] =
            ((const float4*)(G + ((size_t)(b0 + i) * TB + t + 1) * G4H))[o];
      }
    }
    __syncthreads();
    if (tid < 162) {
      const float2 bb = *(const float2*)&bka_s[2 * tid];
      float2 p, v;
      p = *(const float2*)&pka[0 * KAW + 2 * tid];
      v.x = ka0.x + p.x + bb.x; v.y = ka0.y + p.y + bb.y;
      *(float2*)&ka_s[0][2 * tid] = v;
      p = *(const float2*)&pka[1 * KAW + 2 * tid];
      v.x = ka1.x + p.x + bb.x; v.y = ka1.y + p.y + bb.y;
      *(float2*)&ka_s[1][2 * tid] = v;
    }
    __syncthreads();

    // ---- P5: least-used select (waves 0-1, one per batch) + key norms ----
    if (tid < NBAT * 64) {
      const int i = tid >> 6, l = tid & 63;
      unsigned u0v = __float_as_uint(wu_s[i][l]);
      unsigned u1v = __float_as_uint(wu_s[i][l + 64]);
      if (u0v == 0x80000000u) u0v = 0u;
      if (u1v == 0x80000000u) u1v = 0u;
      u0v = (u0v & 0x80000000u) ? ~u0v : (u0v | 0x80000000u);
      u1v = (u1v & 0x80000000u) ? ~u1v : (u1v | 0x80000000u);
      unsigned long long k0 = ((unsigned long long)u0v << 32) | (unsigned)l;
      unsigned long long k1 = ((unsigned long long)u1v << 32) | (unsigned)(l + 64);
#pragma unroll
      for (int rsel = 0; rsel < RR; ++rsel) {
        unsigned long long mn = (k0 < k1) ? k0 : k1;
#pragma unroll
        for (int off = 32; off; off >>= 1) {
          const unsigned long long o = __shfl_xor(mn, off);
          if (o < mn) mn = o;
        }
        const int idx = (int)(mn & 0xFFFFFFFFull);
        if (l == 0) lu_s[i][rsel] = idx;
        if (idx == l)      k0 = ~0ull;
        if (idx == l + 64) k1 = ~0ull;
      }
    } else if (tid < NBAT * 64 + NBAT * RR) {
      const int e = tid - NBAT * 64;
      const int i = e >> 2, q = e & 3;
      float s = 0.f;
#pragma unroll
      for (int d4 = 0; d4 < 10; ++d4) {
        const float4 v = *(const float4*)&ka_s[i][q * DD + 4 * d4];
        s += v.x * v.x + v.y * v.y + v.z * v.z + v.w * v.w;
      }
      kn2_s[i][q] = s;
    }
    __syncthreads();

    // ---- P6: ww = sigma*wr + (1-sigma)*wlu (each lane does both batches) ----
    {
      const int n = tid & (NN - 1);
#pragma unroll
      for (int i = 0; i < NBAT; ++i) {
        const float sg = ka_s[i][320];
        const int l0 = lu_s[i][0], l1 = lu_s[i][1], l2 = lu_s[i][2], l3 = lu_s[i][3];
        const float wlu = (n == l0 || n == l1 || n == l2 || n == l3) ? 1.f : 0.f;
        ww_s[i][tid] = sg * wr_s[i][tid] + (1.f - sg) * wlu;
      }
    }
    __syncthreads();

    // ---- P7: M = M*wlu + ww^T @ add ; fused row-norm (256 lanes: i,n) ----
    if (tid < NBAT * NN) {
      const int i = tid >> 7, n = tid & (NN - 1);
      const int l0 = lu_s[i][0], l1 = lu_s[i][1], l2 = lu_s[i][2], l3 = lu_s[i][3];
      const float wlu = (n == l0 || n == l1 || n == l2 || n == l3) ? 1.f : 0.f;
      const float wwv0 = ww_s[i][n],          wwv1 = ww_s[i][NN + n];
      const float wwv2 = ww_s[i][2 * NN + n], wwv3 = ww_s[i][3 * NN + n];
      float* Mr = &M_s[i][n * MST];
      const float* Ad = &ka_s[i][160];
      float mn2 = 0.f;
#pragma unroll
      for (int d4 = 0; d4 < 10; ++d4) {
        float4 m = *(const float4*)&Mr[4 * d4];
        m.x *= wlu; m.y *= wlu; m.z *= wlu; m.w *= wlu;
        const float4 av0 = *(const float4*)&Ad[0 * DD + 4 * d4];
        const float4 av1 = *(const float4*)&Ad[1 * DD + 4 * d4];
        const float4 av2 = *(const float4*)&Ad[2 * DD + 4 * d4];
        const float4 av3 = *(const float4*)&Ad[3 * DD + 4 * d4];
        m.x += wwv0 * av0.x + wwv1 * av1.x + wwv2 * av2.x + wwv3 * av3.x;
        m.y += wwv0 * av0.y + wwv1 * av1.y + wwv2 * av2.y + wwv3 * av3.y;
        m.z += wwv0 * av0.z + wwv1 * av1.z + wwv2 * av2.z + wwv3 * av3.z;
        m.w += wwv0 * av0.w + wwv1 * av1.w + wwv2 * av2.w + wwv3 * av3.w;
        *(float4*)&Mr[4 * d4] = m;
        mn2 += m.x * m.x + m.y * m.y + m.z * m.z + m.w * m.w;
      }
      Mn2_s[i][n] = mn2;
    }
    __syncthreads();

    // ---- P8: K = cosine(key, M): 512 lanes, each reads one M row, dots 2 keys ----
    {
      const int i = tid >> 8, qq = (tid >> 7) & 1, n = tid & (NN - 1);
      const float* Mr = &M_s[i][n * MST];
      const float* Ky0 = &ka_s[i][qq * DD];
      const float* Ky1 = &ka_s[i][(qq + 2) * DD];
      float s0 = 0.f, s1 = 0.f;
#pragma unroll
      for (int d4 = 0; d4 < 10; ++d4) {
        const float4 mv = *(const float4*)&Mr[4 * d4];
        const float4 k0v = *(const float4*)&Ky0[4 * d4];
        const float4 k1v = *(const float4*)&Ky1[4 * d4];
        s0 += k0v.x * mv.x + k0v.y * mv.y + k0v.z * mv.z + k0v.w * mv.w;
        s1 += k1v.x * mv.x + k1v.y * mv.y + k1v.z * mv.z + k1v.w * mv.w;
      }
      const float mn2 = Mn2_s[i][n];
      Kp[(i << 9) + qq * NN + n]       = s0 / sqrtf(kn2_s[i][qq] * mn2 + 1e-6f);
      Kp[(i << 9) + (qq + 2) * NN + n] = s1 / sqrtf(kn2_s[i][qq + 2] * mn2 + 1e-6f);
    }
    __syncthreads();

    // ---- P9: softmax over N (8 rows, one per wave) ----
    {
      const int w = tid >> 6, l = tid & 63;
      float* Kr = Kp + ((w >> 2) << 9) + (w & 3) * NN;
      const float v0 = Kr[l], v1 = Kr[l + 64];
      float mx = fmaxf(v0, v1);
#pragma unroll
      for (int off = 32; off; off >>= 1) mx = fmaxf(mx, __shfl_xor(mx, off));
      const float e0 = expf(v0 - mx), e1 = expf(v1 - mx);
      float s = e0 + e1;
#pragma unroll
      for (int off = 32; off; off >>= 1) s += __shfl_xor(s, off);
      const float inv = 1.f / s;
      Kr[l] = e0 * inv; Kr[l + 64] = e1 * inv;
    }
    __syncthreads();

    // ---- P10: r = wr_t @ M (80 lanes, broadcast-friendly) ; P11: wu (lanes 256+) ----
    if (tid < NBAT * RR * 10) {
      const int i = tid / (RR * 10), rem = tid - i * (RR * 10);
      const int q = rem / 10, d4 = rem - q * 10;
      const float* Kr = Kp + (i << 9) + q * NN;
      const float* Mb = &M_s[i][4 * d4];
      float4 acc = make_float4(0.f, 0.f, 0.f, 0.f);
      for (int n = 0; n < NN; ++n) {             // same n across lanes: Kr broadcast
        const float kw = Kr[n];
        const float4 mv = *(const float4*)&Mb[n * MST];
        acc.x += kw * mv.x; acc.y += kw * mv.y;
        acc.z += kw * mv.z; acc.w += kw * mv.w;
      }
      const int dbase = (q * DD + 4 * d4) * NBAT + i;
      r2[dbase]            = acc.x;
      r2[dbase + NBAT]     = acc.y;
      r2[dbase + 2 * NBAT] = acc.z;
      r2[dbase + 3 * NBAT] = acc.w;
    } else if (tid >= 256 && tid < 256 + NBAT * NN) {
      const int e = tid - 256;
      const int i = e >> 7, n = e & (NN - 1);
      float s = 0.95f * wu_s[i][n];
#pragma unroll
      for (int q = 0; q < RR; ++q)
        s += Kp[(i << 9) + q * NN + n] + ww_s[i][q * NN + n];
      wu_s[i][n] = s;
    }
    __syncthreads();

    // ---- P12: out (waves 0-1) ; wr <- wr_t (waves 4-7) ----
    if (tid < NBAT * 64) {
      const int i = tid >> 6, l = tid & 63;
      const size_t ob = ((size_t)(b0 + i) * TB + t) * NCLS;
#pragma unroll
      for (int j = 0; j < NCLS; ++j) {
        float p = 0.f;
        for (int k = l; k < HH; k += 64)      p += h2[k * NBAT + i] * Who_s[j * HH + k];
        for (int m = l; m < RR * DD; m += 64) p += r2[m * NBAT + i] * Wro_s[j * RR * DD + m];
#pragma unroll
        for (int off = 32; off; off >>= 1) p += __shfl_xor(p, off);
        if (l == 0) out[ob + j] = p + bo_s[j];
      }
    } else if (tid >= 256) {
      for (int f = tid - 256; f < NBAT * RR * NN; f += 256) (&wr_s[0][0])[f] = Kp[f];
    }
    __syncthreads();
  }
}

// ---------------------------------------------------------------------------
extern "C" void kernel_launch(void* const* d_in, const int* in_sizes, int n_in,
                              void* d_out, int out_size, void* d_ws, size_t ws_size,
                              hipStream_t stream) {
  const float* x    = (const float*)d_in[0];
  const float* Wkey = (const float*)d_in[1];
  const float* bkey = (const float*)d_in[2];
  const float* Wadd = (const float*)d_in[3];
  const float* badd = (const float*)d_in[4];
  const float* Wsig = (const float*)d_in[5];
  const float* bsig = (const float*)d_in[6];
  const float* Who  = (const float*)d_in[7];
  const float* bho  = (const float*)d_in[8];
  const float* Wro  = (const float*)d_in[9];
  const float* bro  = (const float*)d_in[10];
  const float* Wrh  = (const float*)d_in[11];
  const float* brh  = (const float*)d_in[12];
  const float* Wih  = (const float*)d_in[13];
  const float* bih  = (const float*)d_in[14];
  const float* Whh  = (const float*)d_in[15];
  const float* bhh  = (const float*)d_in[16];

  float* ws   = (float*)d_ws;
  float* G    = ws;                       // 25600*800
  float* WhhT = G + (size_t)25600 * 800;  // 160,000
  float* WrhT = WhhT + 160000;            // 32,000
  float* WkaT = WrhT + 32000;             // 64,800
  float* bka  = WkaT + 64800;             // 324

  prep_kernel<<<(160000 + 255) / 256, 256, 0, stream>>>(
      Whh, Wrh, Wkey, Wadd, Wsig, bkey, badd, bsig, WhhT, WrhT, WkaT, bka);

  dim3 gA((G4H + 63) / 64, 25600 / 64);
  gemm_in_kernel<<<gA, 256, 0, stream>>>(x, Wih, bih, bhh, G);

  mann_kernel<<<NBLK, 512, 0, stream>>>(G, WhhT, WrhT, WkaT, bka, brh,
                                        Who, bho, Wro, bro, (float*)d_out);
}

// Round 9
// 3173.520 us; speedup vs baseline: 7.0052x; 1.2238x over previous
//
// MANN/NTM forward — R9: dwordx4 weight streams (fp32 kept; tests request-rate ceiling)
#include <hip/hip_runtime.h>
#include <math.h>

#define TB   100
#define BB   256
#define INF_ 784
#define HH   200
#define RR   4
#define NN   128
#define DD   40
#define NCLS 5
#define G4H  800   // 4*H
#define KAW  324   // 160 key + 160 add + 1 sigma + 3 pad
#define MST  44    // padded M row stride
#define NBAT 2     // batches per block
#define NBLK (BB / NBAT)

__device__ __forceinline__ float sigmoidf_(float x) { return 1.0f / (1.0f + expf(-x)); }

#define ADV(c, CC) { ++(c); if ((c) == (CC)) (c) = 0; }

// 4-slot rotating software pipeline (3 chunks of loads in flight ahead of FMA).
#define PIPE4(CC, OFS, LOADM, FMAM)                                     \
  {                                                                     \
    int chL = (OFS), chF = (OFS);                                       \
    LOADM(w0, chL); ADV(chL, CC); LOADM(w1, chL); ADV(chL, CC);         \
    LOADM(w2, chL); ADV(chL, CC);                                       \
    _Pragma("unroll 1")                                                 \
    for (int g = 0; g < ((CC) - 3) / 4; ++g) {                          \
      LOADM(w3, chL); ADV(chL, CC); FMAM(w0, chF); ADV(chF, CC);        \
      LOADM(w0, chL); ADV(chL, CC); FMAM(w1, chF); ADV(chF, CC);        \
      LOADM(w1, chL); ADV(chL, CC); FMAM(w2, chF); ADV(chF, CC);        \
      LOADM(w2, chL); ADV(chL, CC); FMAM(w3, chF); ADV(chF, CC);        \
    }                                                                   \
    {                                                                   \
      constexpr int REMX = (CC) - 3 - 4 * (((CC) - 3) / 4);             \
      if (REMX >= 1) { LOADM(w3, chL); ADV(chL, CC); }                  \
      FMAM(w0, chF); ADV(chF, CC);                                      \
      if (REMX >= 2) { LOADM(w0, chL); ADV(chL, CC); }                  \
      FMAM(w1, chF); ADV(chF, CC);                                      \
      if (REMX >= 3) { LOADM(w1, chL); ADV(chL, CC); }                  \
      FMAM(w2, chF); ADV(chF, CC);                                      \
      if (REMX >= 1) { FMAM(w3, chF); ADV(chF, CC); }                   \
      if (REMX >= 2) { FMAM(w0, chF); ADV(chF, CC); }                   \
      if (REMX >= 3) { FMAM(w1, chF); ADV(chF, CC); }                   \
    }                                                                   \
  }

// ---------------------------------------------------------------------------
// Prep: transpose weights into GEMV-friendly (k-major) layouts in workspace.
// ---------------------------------------------------------------------------
__global__ __launch_bounds__(256) void prep_kernel(
    const float* __restrict__ Whh, const float* __restrict__ Wrh,
    const float* __restrict__ Wkey, const float* __restrict__ Wadd,
    const float* __restrict__ Wsig, const float* __restrict__ bkey,
    const float* __restrict__ badd, const float* __restrict__ bsig,
    float* __restrict__ WhhT, float* __restrict__ WrhT,
    float* __restrict__ WkaT, float* __restrict__ bka)
{
  const int tid = blockIdx.x * 256 + threadIdx.x;
  if (tid < 160000) {            // Whh (800,200) -> WhhT (200,800)
    const int j = tid / 200, k = tid - j * 200;
    WhhT[k * G4H + j] = Whh[tid];
  }
  if (tid < 32000) {             // Wrh (200,160) -> WrhT (160,200)
    const int k = tid / 160, m = tid - k * 160;
    WrhT[m * HH + k] = Wrh[tid];
  }
  if (tid < 200 * KAW) {         // [Wkey(160,200)|Wadd(160,200)|Wsig(1,200)]^T
    const int k = tid / KAW, j = tid - k * KAW;
    float v = 0.0f;
    if (j < 160)       v = Wkey[j * HH + k];
    else if (j < 320)  v = Wadd[(j - 160) * HH + k];
    else if (j == 320) v = Wsig[k];
    WkaT[tid] = v;
  }
  if (tid < KAW) {
    float v = 0.0f;
    if (tid < 160)       v = bkey[tid];
    else if (tid < 320)  v = badd[tid - 160];
    else if (tid == 320) v = bsig[0];
    bka[tid] = v;
  }
}

// ---------------------------------------------------------------------------
// Big GEMM: G[m, j] = sum_k x[m,k]*Wih[j,k] + bih[j] + bhh[j]
// ---------------------------------------------------------------------------
__global__ __launch_bounds__(256) void gemm_in_kernel(
    const float* __restrict__ X, const float* __restrict__ Wih,
    const float* __restrict__ bih, const float* __restrict__ bhh,
    float* __restrict__ G)
{
  __shared__ float As[16 * 68];
  __shared__ float Bs[16 * 68];
  const int tid  = threadIdx.x;
  const int tx   = tid & 15, ty = tid >> 4;
  const int lrow = tid >> 2, lk = (tid & 3) * 4;
  const int n0 = blockIdx.x * 64;
  const int m0 = blockIdx.y * 64;
  const int jg = n0 + lrow;
  const float* Xp = X   + (size_t)(m0 + lrow) * INF_ + lk;
  const float* Wp = Wih + (size_t)jg * INF_ + lk;

  float acc[4][4];
#pragma unroll
  for (int i = 0; i < 4; ++i)
#pragma unroll
    for (int j = 0; j < 4; ++j) acc[i][j] = 0.f;

  for (int k0 = 0; k0 < INF_; k0 += 16) {
    const float4 a = *(const float4*)(Xp + k0);
    const float4 b = (jg < G4H) ? *(const float4*)(Wp + k0)
                                : make_float4(0.f, 0.f, 0.f, 0.f);
    __syncthreads();
    const float av[4] = {a.x, a.y, a.z, a.w};
    const float bv[4] = {b.x, b.y, b.z, b.w};
#pragma unroll
    for (int u = 0; u < 4; ++u) {
      As[(lk + u) * 68 + lrow] = av[u];
      Bs[(lk + u) * 68 + lrow] = bv[u];
    }
    __syncthreads();
#pragma unroll
    for (int k = 0; k < 16; ++k) {
      const float4 a4 = *(const float4*)&As[k * 68 + ty * 4];
      const float4 b4 = *(const float4*)&Bs[k * 68 + tx * 4];
      const float aa[4] = {a4.x, a4.y, a4.z, a4.w};
      const float bb[4] = {b4.x, b4.y, b4.z, b4.w};
#pragma unroll
      for (int i = 0; i < 4; ++i)
#pragma unroll
        for (int j = 0; j < 4; ++j) acc[i][j] += aa[i] * bb[j];
    }
  }
  const int jc = n0 + tx * 4;
  if (jc < G4H) {
    float bs[4];
#pragma unroll
    for (int u = 0; u < 4; ++u) bs[u] = bih[jc + u] + bhh[jc + u];
#pragma unroll
    for (int i = 0; i < 4; ++i) {
      const size_t m = (size_t)m0 + ty * 4 + i;
      const float4 v = make_float4(acc[i][0] + bs[0], acc[i][1] + bs[1],
                                   acc[i][2] + bs[2], acc[i][3] + bs[3]);
      *(float4*)(G + m * G4H + jc) = v;
    }
  }
}

// ---------------------------------------------------------------------------
// Recurrence: one block (512 thr) per 2 batch elements; 128 blocks.
// GEMV weight streams use dwordx4 loads (lane owns 4 output columns).
// ---------------------------------------------------------------------------
__global__ __launch_bounds__(512, 2) void mann_kernel(
    const float* __restrict__ G, const float* __restrict__ WhhT,
    const float* __restrict__ WrhT, const float* __restrict__ WkaT,
    const float* __restrict__ bka, const float* __restrict__ brh,
    const float* __restrict__ Who, const float* __restrict__ bho,
    const float* __restrict__ Wro, const float* __restrict__ bro,
    float* __restrict__ out)
{
  __shared__ __attribute__((aligned(16))) float M_s[NBAT][NN * MST];
  __shared__ __attribute__((aligned(16))) float h2[HH * NBAT];   // [k*2+i]
  __shared__ __attribute__((aligned(16))) float c2[HH * NBAT];
  __shared__ __attribute__((aligned(16))) float r2[RR * DD * NBAT];
  __shared__ __attribute__((aligned(16))) float brh_s[HH];
  __shared__ float wr_s[NBAT][RR * NN];
  __shared__ float ww_s[NBAT][RR * NN];
  __shared__ float wu_s[NBAT][NN];
  __shared__ float Mn2_s[NBAT][NN];
  __shared__ float kn2_s[NBAT][RR];
  __shared__ __attribute__((aligned(16))) float gates_s[NBAT][G4H];
  __shared__ __attribute__((aligned(16))) float ka_s[NBAT][KAW];
  __shared__ __attribute__((aligned(16))) float bka_s[KAW];
  __shared__ __attribute__((aligned(16))) float Gbuf_s[NBAT][G4H];
  __shared__ float Who_s[NCLS * HH], Wro_s[NCLS * RR * DD], bo_s[NCLS];
  __shared__ int   lu_s[NBAT][RR];

  // Aliases into the gates region (temporally disjoint):
  float*  Kp   = &gates_s[0][0];          // [2][512] wr_t (P8..P12)
  float4* pkA4 = (float4*)&gates_s[0][0]; // P1 partials batch0 (50 float4)
  float4* pkB4 = pkA4 + 50;               // P1 partials batch1
  float4* pka4 = (float4*)&gates_s[0][0]; // P4 partials: [0..80]=b0, [81..161]=b1

  const int tid = threadIdx.x;
  const int b0  = blockIdx.x * NBAT;

  // ---- init ----
  for (int e = tid; e < NBAT * NN * MST; e += 512) (&M_s[0][0])[e] = 0.f;
  for (int e = tid; e < NBAT * RR * NN; e += 512) (&wr_s[0][0])[e] = 0.f;
  if (tid < NBAT * NN) (&wu_s[0][0])[tid] = 0.f;
  for (int e = tid; e < HH * NBAT; e += 512) { h2[e] = 0.f; c2[e] = 0.f; }
  if (tid < RR * DD * NBAT) r2[tid] = 0.f;
  if (tid < HH) brh_s[tid] = brh[tid];
  if (tid < KAW) bka_s[tid] = bka[tid];
  for (int e = tid; e < NCLS * HH; e += 512) Who_s[e] = Who[e];
  for (int e = tid; e < NCLS * RR * DD; e += 512) Wro_s[e] = Wro[e];
  if (tid < NCLS) bo_s[tid] = bho[tid] + bro[tid];
  if (tid < NBAT * 200) {
    const int i = tid / 200, o = tid - i * 200;
    ((float4*)&Gbuf_s[i][0])[o] =
        ((const float4*)(G + ((size_t)(b0 + i) * TB) * G4H))[o];
  }
  __syncthreads();

  const int ofs1 = (int)((blockIdx.x * 3u) % 10u);
  const int ofs2 = (int)((blockIdx.x * 7u) % 25u);
  const int ofs4 = (int)((blockIdx.x * 5u) % 25u);

#pragma clang loop unroll(disable)
  for (int t = 0; t < TB; ++t) {
    float4 a0v = make_float4(0.f, 0.f, 0.f, 0.f);
    float4 a1v = make_float4(0.f, 0.f, 0.f, 0.f);

    // ---- P1: h += r @ Wrh^T + brh (100 lanes: 50 j4 x 2 k-halves, dwordx4) ----
    if (tid < 100) {
      const int kh = tid / 50, j4 = tid - kh * 50;
      const int kbeg = kh * 80;
      const float4* __restrict__ Wr4 = (const float4*)WrhT + (size_t)kbeg * 50 + j4;
      float4 w0[8], w1[8], w2[8], w3[8];
#define P1_LOAD(B, CH) { const int mm = (CH) * 8; _Pragma("unroll") \
      for (int u = 0; u < 8; ++u) B[u] = Wr4[(mm + u) * 50]; }
#define P1_FMA(B, CH) { const int kb = kbeg + (CH) * 8; _Pragma("unroll") \
      for (int u = 0; u < 8; ++u) { const float2 rk = *(const float2*)&r2[(kb + u) * 2]; \
        a0v.x += rk.x * B[u].x; a0v.y += rk.x * B[u].y; a0v.z += rk.x * B[u].z; a0v.w += rk.x * B[u].w; \
        a1v.x += rk.y * B[u].x; a1v.y += rk.y * B[u].y; a1v.z += rk.y * B[u].z; a1v.w += rk.y * B[u].w; } }
      PIPE4(10, ofs1, P1_LOAD, P1_FMA)
      if (kh) { pkA4[j4] = a0v; pkB4[j4] = a1v; }
    }
    __syncthreads();
    if (tid < 50) {
      const int j4 = tid;
      const float4 pA = pkA4[j4], pB = pkB4[j4];
      const float4 brv = ((const float4*)brh_s)[j4];
      float4 hv0 = *(const float4*)&h2[8 * j4];
      float4 hv1 = *(const float4*)&h2[8 * j4 + 4];
      hv0.x += brv.x + a0v.x + pA.x;  hv0.y += brv.x + a1v.x + pB.x;
      hv0.z += brv.y + a0v.y + pA.y;  hv0.w += brv.y + a1v.y + pB.y;
      hv1.x += brv.z + a0v.z + pA.z;  hv1.y += brv.z + a1v.z + pB.z;
      hv1.z += brv.w + a0v.w + pA.w;  hv1.w += brv.w + a1v.w + pB.w;
      *(float4*)&h2[8 * j4]     = hv0;
      *(float4*)&h2[8 * j4 + 4] = hv1;
    }
    __syncthreads();

    // ---- P2: gates = Gbuf + h @ Whh^T (200 lanes x dwordx4, 2 batches) ----
    if (tid < 200) {
      const float4* __restrict__ Wh4 = (const float4*)WhhT + tid;
      float4 g0 = *(const float4*)&Gbuf_s[0][4 * tid];
      float4 g1 = *(const float4*)&Gbuf_s[1][4 * tid];
      float4 w0[8], w1[8], w2[8], w3[8];
#define P2_LOAD(B, CH) { const int kk = (CH) * 8; _Pragma("unroll") \
      for (int u = 0; u < 8; ++u) B[u] = Wh4[(kk + u) * 200]; }
#define P2_FMA(B, CH) { const int kc = (CH) * 8; _Pragma("unroll") \
      for (int u = 0; u < 8; ++u) { const float2 hk = *(const float2*)&h2[(kc + u) * 2]; \
        g0.x += hk.x * B[u].x; g0.y += hk.x * B[u].y; g0.z += hk.x * B[u].z; g0.w += hk.x * B[u].w; \
        g1.x += hk.y * B[u].x; g1.y += hk.y * B[u].y; g1.z += hk.y * B[u].z; g1.w += hk.y * B[u].w; } }
      PIPE4(25, ofs2, P2_LOAD, P2_FMA)
      *(float4*)&gates_s[0][4 * tid] = g0;
      *(float4*)&gates_s[1][4 * tid] = g1;
    }
    __syncthreads();

    // ---- P3: LSTM pointwise (400 items) ----
    if (tid < NBAT * HH) {
      const int i = tid / HH, k = tid - i * HH;
      const float ig = sigmoidf_(gates_s[i][k]);
      const float fg = sigmoidf_(gates_s[i][HH + k]);
      const float gg = tanhf(gates_s[i][2 * HH + k]);
      const float og = sigmoidf_(gates_s[i][3 * HH + k]);
      const float cn = fg * c2[k * NBAT + i] + ig * gg;
      c2[k * NBAT + i] = cn;
      h2[k * NBAT + i] = og * tanhf(cn);
    }
    __syncthreads();

    // ---- P4: [key|add|sigma] = bka + h @ Wka^T (162 lanes x dwordx4) ;
    //      lanes>=384 prefetch G(t+1) ----
    float4 kav0 = make_float4(0.f, 0.f, 0.f, 0.f);
    float4 kav1 = make_float4(0.f, 0.f, 0.f, 0.f);
    if (tid < 162) {
      const int kh = tid / 81, j4 = tid - kh * 81;
      const int kbeg = kh * 100;
      const float4* __restrict__ Wk4 = (const float4*)WkaT + (size_t)kbeg * 81 + j4;
      float4 w0[4], w1[4], w2[4], w3[4];
#define P4_LOAD(B, CH) { const int kk = (CH) * 4; _Pragma("unroll") \
      for (int u = 0; u < 4; ++u) B[u] = Wk4[(kk + u) * 81]; }
#define P4_FMA(B, CH) { const int kc = kbeg + (CH) * 4; _Pragma("unroll") \
      for (int u = 0; u < 4; ++u) { const float2 hk = *(const float2*)&h2[(kc + u) * 2]; \
        kav0.x += hk.x * B[u].x; kav0.y += hk.x * B[u].y; kav0.z += hk.x * B[u].z; kav0.w += hk.x * B[u].w; \
        kav1.x += hk.y * B[u].x; kav1.y += hk.y * B[u].y; kav1.z += hk.y * B[u].z; kav1.w += hk.y * B[u].w; } }
      PIPE4(25, ofs4, P4_LOAD, P4_FMA)
      if (kh) { pka4[j4] = kav0; pka4[81 + j4] = kav1; }
    } else if (tid >= 384 && t + 1 < TB) {
      for (int idx = tid - 384; idx < NBAT * 200; idx += 128) {
        const int i = idx / 200, o = idx - i * 200;
        ((float4*)&Gbuf_s[i][0])[o] =
            ((const float4*)(G + ((size_t)(b0 + i) * TB + t + 1) * G4H))[o];
      }
    }
    __syncthreads();
    if (tid < 81) {
      const float4 bbv = ((const float4*)bka_s)[tid];
      const float4 p0 = pka4[tid], p1 = pka4[81 + tid];
      float4 v0, v1;
      v0.x = kav0.x + p0.x + bbv.x; v0.y = kav0.y + p0.y + bbv.y;
      v0.z = kav0.z + p0.z + bbv.z; v0.w = kav0.w + p0.w + bbv.w;
      v1.x = kav1.x + p1.x + bbv.x; v1.y = kav1.y + p1.y + bbv.y;
      v1.z = kav1.z + p1.z + bbv.z; v1.w = kav1.w + p1.w + bbv.w;
      *(float4*)&ka_s[0][4 * tid] = v0;
      *(float4*)&ka_s[1][4 * tid] = v1;
    }
    __syncthreads();

    // ---- P5: least-used select (waves 0-1, one per batch) + key norms ----
    if (tid < NBAT * 64) {
      const int i = tid >> 6, l = tid & 63;
      unsigned u0v = __float_as_uint(wu_s[i][l]);
      unsigned u1v = __float_as_uint(wu_s[i][l + 64]);
      if (u0v == 0x80000000u) u0v = 0u;
      if (u1v == 0x80000000u) u1v = 0u;
      u0v = (u0v & 0x80000000u) ? ~u0v : (u0v | 0x80000000u);
      u1v = (u1v & 0x80000000u) ? ~u1v : (u1v | 0x80000000u);
      unsigned long long k0 = ((unsigned long long)u0v << 32) | (unsigned)l;
      unsigned long long k1 = ((unsigned long long)u1v << 32) | (unsigned)(l + 64);
#pragma unroll
      for (int rsel = 0; rsel < RR; ++rsel) {
        unsigned long long mn = (k0 < k1) ? k0 : k1;
#pragma unroll
        for (int off = 32; off; off >>= 1) {
          const unsigned long long o = __shfl_xor(mn, off);
          if (o < mn) mn = o;
        }
        const int idx = (int)(mn & 0xFFFFFFFFull);
        if (l == 0) lu_s[i][rsel] = idx;
        if (idx == l)      k0 = ~0ull;
        if (idx == l + 64) k1 = ~0ull;
      }
    } else if (tid < NBAT * 64 + NBAT * RR) {
      const int e = tid - NBAT * 64;
      const int i = e >> 2, q = e & 3;
      float s = 0.f;
#pragma unroll
      for (int d4 = 0; d4 < 10; ++d4) {
        const float4 v = *(const float4*)&ka_s[i][q * DD + 4 * d4];
        s += v.x * v.x + v.y * v.y + v.z * v.z + v.w * v.w;
      }
      kn2_s[i][q] = s;
    }
    __syncthreads();

    // ---- P6: ww = sigma*wr + (1-sigma)*wlu ----
    {
      const int n = tid & (NN - 1);
#pragma unroll
      for (int i = 0; i < NBAT; ++i) {
        const float sg = ka_s[i][320];
        const int l0 = lu_s[i][0], l1 = lu_s[i][1], l2 = lu_s[i][2], l3 = lu_s[i][3];
        const float wlu = (n == l0 || n == l1 || n == l2 || n == l3) ? 1.f : 0.f;
        ww_s[i][tid] = sg * wr_s[i][tid] + (1.f - sg) * wlu;
      }
    }
    __syncthreads();

    // ---- P7: M = M*wlu + ww^T @ add ; fused row-norm (256 lanes: i,n) ----
    if (tid < NBAT * NN) {
      const int i = tid >> 7, n = tid & (NN - 1);
      const int l0 = lu_s[i][0], l1 = lu_s[i][1], l2 = lu_s[i][2], l3 = lu_s[i][3];
      const float wlu = (n == l0 || n == l1 || n == l2 || n == l3) ? 1.f : 0.f;
      const float wwv0 = ww_s[i][n],          wwv1 = ww_s[i][NN + n];
      const float wwv2 = ww_s[i][2 * NN + n], wwv3 = ww_s[i][3 * NN + n];
      float* Mr = &M_s[i][n * MST];
      const float* Ad = &ka_s[i][160];
      float mn2 = 0.f;
#pragma unroll
      for (int d4 = 0; d4 < 10; ++d4) {
        float4 m = *(const float4*)&Mr[4 * d4];
        m.x *= wlu; m.y *= wlu; m.z *= wlu; m.w *= wlu;
        const float4 av0 = *(const float4*)&Ad[0 * DD + 4 * d4];
        const float4 av1 = *(const float4*)&Ad[1 * DD + 4 * d4];
        const float4 av2 = *(const float4*)&Ad[2 * DD + 4 * d4];
        const float4 av3 = *(const float4*)&Ad[3 * DD + 4 * d4];
        m.x += wwv0 * av0.x + wwv1 * av1.x + wwv2 * av2.x + wwv3 * av3.x;
        m.y += wwv0 * av0.y + wwv1 * av1.y + wwv2 * av2.y + wwv3 * av3.y;
        m.z += wwv0 * av0.z + wwv1 * av1.z + wwv2 * av2.z + wwv3 * av3.z;
        m.w += wwv0 * av0.w + wwv1 * av1.w + wwv2 * av2.w + wwv3 * av3.w;
        *(float4*)&Mr[4 * d4] = m;
        mn2 += m.x * m.x + m.y * m.y + m.z * m.z + m.w * m.w;
      }
      Mn2_s[i][n] = mn2;
    }
    __syncthreads();

    // ---- P8: K = cosine(key, M): 512 lanes, each reads one M row, 2 keys ----
    {
      const int i = tid >> 8, qq = (tid >> 7) & 1, n = tid & (NN - 1);
      const float* Mr = &M_s[i][n * MST];
      const float* Ky0 = &ka_s[i][qq * DD];
      const float* Ky1 = &ka_s[i][(qq + 2) * DD];
      float s0 = 0.f, s1 = 0.f;
#pragma unroll
      for (int d4 = 0; d4 < 10; ++d4) {
        const float4 mv = *(const float4*)&Mr[4 * d4];
        const float4 k0v = *(const float4*)&Ky0[4 * d4];
        const float4 k1v = *(const float4*)&Ky1[4 * d4];
        s0 += k0v.x * mv.x + k0v.y * mv.y + k0v.z * mv.z + k0v.w * mv.w;
        s1 += k1v.x * mv.x + k1v.y * mv.y + k1v.z * mv.z + k1v.w * mv.w;
      }
      const float mn2 = Mn2_s[i][n];
      Kp[(i << 9) + qq * NN + n]       = s0 / sqrtf(kn2_s[i][qq] * mn2 + 1e-6f);
      Kp[(i << 9) + (qq + 2) * NN + n] = s1 / sqrtf(kn2_s[i][qq + 2] * mn2 + 1e-6f);
    }
    __syncthreads();

    // ---- P9: softmax over N (8 rows, one per wave) ----
    {
      const int w = tid >> 6, l = tid & 63;
      float* Kr = Kp + ((w >> 2) << 9) + (w & 3) * NN;
      const float v0 = Kr[l], v1 = Kr[l + 64];
      float mx = fmaxf(v0, v1);
#pragma unroll
      for (int off = 32; off; off >>= 1) mx = fmaxf(mx, __shfl_xor(mx, off));
      const float e0 = expf(v0 - mx), e1 = expf(v1 - mx);
      float s = e0 + e1;
#pragma unroll
      for (int off = 32; off; off >>= 1) s += __shfl_xor(s, off);
      const float inv = 1.f / s;
      Kr[l] = e0 * inv; Kr[l + 64] = e1 * inv;
    }
    __syncthreads();

    // ---- P10: r = wr_t @ M (80 lanes, broadcast) ; P11: wu (lanes 256+) ----
    if (tid < NBAT * RR * 10) {
      const int i = tid / (RR * 10), rem = tid - i * (RR * 10);
      const int q = rem / 10, d4 = rem - q * 10;
      const float* Kr = Kp + (i << 9) + q * NN;
      const float* Mb = &M_s[i][4 * d4];
      float4 acc = make_float4(0.f, 0.f, 0.f, 0.f);
      for (int n = 0; n < NN; ++n) {
        const float kw = Kr[n];
        const float4 mv = *(const float4*)&Mb[n * MST];
        acc.x += kw * mv.x; acc.y += kw * mv.y;
        acc.z += kw * mv.z; acc.w += kw * mv.w;
      }
      const int dbase = (q * DD + 4 * d4) * NBAT + i;
      r2[dbase]            = acc.x;
      r2[dbase + NBAT]     = acc.y;
      r2[dbase + 2 * NBAT] = acc.z;
      r2[dbase + 3 * NBAT] = acc.w;
    } else if (tid >= 256 && tid < 256 + NBAT * NN) {
      const int e = tid - 256;
      const int i = e >> 7, n = e & (NN - 1);
      float s = 0.95f * wu_s[i][n];
#pragma unroll
      for (int q = 0; q < RR; ++q)
        s += Kp[(i << 9) + q * NN + n] + ww_s[i][q * NN + n];
      wu_s[i][n] = s;
    }
    __syncthreads();

    // ---- P12: out (waves 0-1) ; wr <- wr_t (waves 4-7) ----
    if (tid < NBAT * 64) {
      const int i = tid >> 6, l = tid & 63;
      const size_t ob = ((size_t)(b0 + i) * TB + t) * NCLS;
#pragma unroll
      for (int j = 0; j < NCLS; ++j) {
        float p = 0.f;
        for (int k = l; k < HH; k += 64)      p += h2[k * NBAT + i] * Who_s[j * HH + k];
        for (int m = l; m < RR * DD; m += 64) p += r2[m * NBAT + i] * Wro_s[j * RR * DD + m];
#pragma unroll
        for (int off = 32; off; off >>= 1) p += __shfl_xor(p, off);
        if (l == 0) out[ob + j] = p + bo_s[j];
      }
    } else if (tid >= 256) {
      for (int f = tid - 256; f < NBAT * RR * NN; f += 256) (&wr_s[0][0])[f] = Kp[f];
    }
    __syncthreads();
  }
}

// ---------------------------------------------------------------------------
extern "C" void kernel_launch(void* const* d_in, const int* in_sizes, int n_in,
                              void* d_out, int out_size, void* d_ws, size_t ws_size,
                              hipStream_t stream) {
  const float* x    = (const float*)d_in[0];
  const float* Wkey = (const float*)d_in[1];
  const float* bkey = (const float*)d_in[2];
  const float* Wadd = (const float*)d_in[3];
  const float* badd = (const float*)d_in[4];
  const float* Wsig = (const float*)d_in[5];
  const float* bsig = (const float*)d_in[6];
  const float* Who  = (const float*)d_in[7];
  const float* bho  = (const float*)d_in[8];
  const float* Wro  = (const float*)d_in[9];
  const float* bro  = (const float*)d_in[10];
  const float* Wrh  = (const float*)d_in[11];
  const float* brh  = (const float*)d_in[12];
  const float* Wih  = (const float*)d_in[13];
  const float* bih  = (const float*)d_in[14];
  const float* Whh  = (const float*)d_in[15];
  const float* bhh  = (const float*)d_in[16];

  float* ws   = (float*)d_ws;
  float* G    = ws;                       // 25600*800
  float* WhhT = G + (size_t)25600 * 800;  // 160,000
  float* WrhT = WhhT + 160000;            // 32,000
  float* WkaT = WrhT + 32000;             // 64,800
  float* bka  = WkaT + 64800;             // 324

  prep_kernel<<<(160000 + 255) / 256, 256, 0, stream>>>(
      Whh, Wrh, Wkey, Wadd, Wsig, bkey, badd, bsig, WhhT, WrhT, WkaT, bka);

  dim3 gA((G4H + 63) / 64, 25600 / 64);
  gemm_in_kernel<<<gA, 256, 0, stream>>>(x, Wih, bih, bhh, G);

  mann_kernel<<<NBLK, 512, 0, stream>>>(G, WhhT, WrhT, WkaT, bka, brh,
                                        Who, bho, Wro, bro, (float*)d_out);
}